// Round 4
// baseline (2482.186 us; speedup 1.0000x reference)
//
#include <hip/hip_runtime.h>

#define SEQ 1024
#define NHEAD 16
#define DHEAD 64

__device__ __forceinline__ float bflo(unsigned int x){ return __uint_as_float(x << 16); }
__device__ __forceinline__ float bfhi(unsigned int x){ return __uint_as_float(x & 0xffff0000u); }
__device__ __forceinline__ unsigned short f2bf(float f){
  unsigned int u = __float_as_uint(f);
  u += 0x7fffu + ((u >> 16) & 1u);
  return (unsigned short)(u >> 16);
}

// ---------------- RoPE cos/sin table: rope[pos*64 + i]=cos, [pos*64+32+i]=sin ----------------
__global__ void rope_table_kernel(float* __restrict__ rope){
  int idx = blockIdx.x * 256 + threadIdx.x;
  if (idx >= 2048 * 32) return;
  int pos = idx >> 5, i = idx & 31;
  double freq = pow(10000.0, -(double)i / 32.0);
  double a = (double)pos * freq;
  rope[pos * 64 + i]      = (float)cos(a);
  rope[pos * 64 + 32 + i] = (float)sin(a);
}

// ------- out[M=2048,1024] = A[2048,1024] @ W[1024,1024]^T + bias; mode1: RoPE epilogue -------
__global__ __launch_bounds__(256) void gemm_kernel(
    const float* __restrict__ A, const float* __restrict__ W,
    const float* __restrict__ bias, float* __restrict__ out,
    const float* __restrict__ rope, const int* __restrict__ pos_ids, int mode)
{
  __shared__ float As[64][68];
  __shared__ float Ws[64][68];
  int t = threadIdx.x;
  int tx = t & 15, ty = t >> 4;
  int row0 = blockIdx.y << 6, col0 = blockIdx.x << 6;
  float acc[4][4];
  #pragma unroll
  for (int a = 0; a < 4; a++)
    #pragma unroll
    for (int c = 0; c < 4; c++) acc[a][c] = 0.f;
  float bvv[4];
  #pragma unroll
  for (int j = 0; j < 4; j++) bvv[j] = bias[col0 + tx + 16*j];

  for (int kt = 0; kt < 1024; kt += 64){
    #pragma unroll
    for (int jj = 0; jj < 4; jj++){
      int flat = t + jj*256;
      int r = flat >> 4, c4 = (flat & 15) << 2;
      *(float4*)&As[r][c4] = *(const float4*)(A + (size_t)(row0 + r)*1024 + kt + c4);
      *(float4*)&Ws[r][c4] = *(const float4*)(W + (size_t)(col0 + r)*1024 + kt + c4);
    }
    __syncthreads();
    #pragma unroll
    for (int i4 = 0; i4 < 16; i4++){
      float4 a4[4], b4[4];
      #pragma unroll
      for (int j = 0; j < 4; j++){
        a4[j] = *(float4*)&As[ty + 16*j][i4 << 2];
        b4[j] = *(float4*)&Ws[tx + 16*j][i4 << 2];
      }
      #pragma unroll
      for (int jr = 0; jr < 4; jr++)
        #pragma unroll
        for (int jc = 0; jc < 4; jc++)
          acc[jr][jc] += a4[jr].x*b4[jc].x + a4[jr].y*b4[jc].y + a4[jr].z*b4[jc].z + a4[jr].w*b4[jc].w;
    }
    __syncthreads();
  }
  #pragma unroll
  for (int jr = 0; jr < 4; jr++)
    #pragma unroll
    for (int jc = 0; jc < 4; jc++)
      As[ty + 16*jr][tx + 16*jc] = acc[jr][jc] + bvv[jc];
  __syncthreads();
  #pragma unroll
  for (int jj = 0; jj < 16; jj++){
    int flat = t + jj*256;
    int r = flat >> 6, c = flat & 63;
    int grow = row0 + r;
    float x = As[r][c];
    if (mode){
      float p = As[r][c ^ 32];
      int pos = pos_ids[grow];
      pos = pos < 0 ? 0 : (pos > 2047 ? 2047 : pos);
      int i = c & 31;
      float cs = rope[pos*64 + i];
      float sn = rope[pos*64 + 32 + i];
      x = (c < 32) ? (x*cs - p*sn) : (x*cs + p*sn);
    }
    out[(size_t)grow*1024 + col0 + c] = x;
  }
}

// ---------------- attention v2: one block per (b,q) row, 256-key chunks, ILP dots ----------------
__global__ __launch_bounds__(512, 4) void attn_kernel(
    const float* __restrict__ qw, const float* __restrict__ kw,
    const float* __restrict__ vw,
    const float* __restrict__ relk, const float* __restrict__ relv,
    const float* __restrict__ wpre_g, const float* __restrict__ wpost_g,
    const int* __restrict__ qpos_g, const int* __restrict__ kpos_g,
    float* __restrict__ ctx)
{
  __shared__ float qrow_s[16][68];
  __shared__ __align__(4) unsigned short relvb_s[129][66];  // rel_v rows 128..256 as bf16
  __shared__ float qrel_s[16][132];
  __shared__ float u_s[16][260];     // stride 260 -> bank 4n+j, <=2-way (free)
  __shared__ float w2_s[16][260];
  __shared__ int   rels_c[256];
  __shared__ float wpre_s[16][17];
  __shared__ float wpost_s[16][17];
  __shared__ float red[32][16];
  __shared__ float mrow[16];
  __shared__ float invl[16];

  int t = threadIdx.x;
  int bid = blockIdx.x;
  int b = bid & 1;
  int q = (SEQ - 1) - (bid >> 1);   // longest rows dispatched first
  size_t browq = (size_t)(b*SEQ + q);
  int m16 = t & 15, slot = t >> 4;  // slot 0..31

  for (int f = t; f < 1024; f += 512)
    qrow_s[f >> 6][f & 63] = qw[browq*1024 + f];
  if (t < 256) wpre_s[t >> 4][t & 15] = wpre_g[t];
  else { int u = t - 256; wpost_s[u >> 4][u & 15] = wpost_g[u]; }
  for (int e = t; e < 129*64; e += 512){
    int r = e >> 6, d = e & 63;
    relvb_s[r][d] = f2bf(relv[(size_t)(128 + r)*64 + d]);
  }
  __syncthreads();

  // qrel[n][r] = q_n . rel_k[128+r]  (causal => only rows 128..256 used)
  for (int r = slot; r < 129; r += 32){
    const float* rk = relk + (size_t)(128 + r)*64;
    float s = 0.f;
    #pragma unroll
    for (int d4 = 0; d4 < 64; d4 += 4){
      float4 pv = *(const float4*)(rk + d4);
      float4 qv = *(const float4*)&qrow_s[m16][d4];
      s += qv.x*pv.x + qv.y*pv.y + qv.z*pv.z + qv.w*pv.w;
    }
    qrel_s[m16][r] = s;
  }
  int qp = qpos_g[b*SEQ + q];
  __syncthreads();

  int nk = q + 1;
  int nct = (nk + 255) >> 8;        // <= 4 chunks of 256 keys
  float sreg[32];
  #pragma unroll
  for (int i = 0; i < 32; i++) sreg[i] = -1e30f;

  // ---- scores: u = (q.k + q.rel_k)/8, pre-softmax head mix; 2 barriers per 256 keys ----
  for (int ci = 0; ci < nct; ci++){
    int kb = ci << 8;
    const float* kp0[8];
    float sacc[8];
    #pragma unroll
    for (int jj = 0; jj < 8; jj++){
      sacc[jj] = 0.f;
      int k = kb + slot + 32*jj;                    // always <= 1023 (in-bounds)
      kp0[jj] = kw + ((size_t)(b*SEQ + k))*1024 + m16*64;
    }
    #pragma unroll 4
    for (int d4 = 0; d4 < 64; d4 += 4){
      float4 qv = *(const float4*)&qrow_s[m16][d4];
      #pragma unroll
      for (int jj = 0; jj < 8; jj++){
        float4 kv = *(const float4*)(kp0[jj] + d4);
        sacc[jj] += qv.x*kv.x + qv.y*kv.y + qv.z*kv.z + qv.w*kv.w;
      }
    }
    #pragma unroll
    for (int jj = 0; jj < 8; jj++){
      int j = slot + 32*jj, k = kb + j;
      float uval = 0.f;
      if (k < nk){
        int kpv = kpos_g[b*SEQ + k];
        int rd = qp - kpv; rd = rd > 128 ? 128 : (rd < 0 ? 0 : rd);
        uval = (sacc[jj] + qrel_s[m16][rd]) * 0.125f;
      }
      u_s[m16][j] = uval;
    }
    __syncthreads();
    #pragma unroll
    for (int jj = 0; jj < 8; jj++){
      int j = slot + 32*jj, k = kb + j;
      if (k < nk){
        float a = 0.f;
        #pragma unroll
        for (int n = 0; n < 16; n++) a += u_s[n][j] * wpre_s[n][m16];
        sreg[ci*8 + jj] = a;
      }
    }
    __syncthreads();
  }

  // ---- exact softmax per head row ----
  float loc = -1e30f;
  #pragma unroll
  for (int i = 0; i < 32; i++) loc = fmaxf(loc, sreg[i]);
  red[slot][m16] = loc;
  __syncthreads();
  if (t < 16){
    float v = -1e30f;
    #pragma unroll
    for (int s2 = 0; s2 < 32; s2++) v = fmaxf(v, red[s2][t]);
    mrow[t] = v;
  }
  __syncthreads();
  float mm = mrow[m16];
  float ls = 0.f;
  #pragma unroll
  for (int i = 0; i < 32; i++){
    float arg = fmaxf(sreg[i] - mm, -80.f);   // masked -> exp(-80) ~ 1.8e-35
    float p = __expf(arg);
    sreg[i] = p;
    ls += p;
  }
  red[slot][m16] = ls;
  __syncthreads();
  if (t < 16){
    float v = 0.f;
    #pragma unroll
    for (int s2 = 0; s2 < 32; s2++) v += red[s2][t];
    invl[t] = 1.f / v;
  }
  __syncthreads();
  if (t < 256){ int m = t >> 4, n = t & 15; wpost_s[m][n] *= invl[m]; }  // fold 1/l
  __syncthreads();

  // ---- post-mix + PV with fused rel_v; 3 barriers per 256 keys ----
  int nn = t >> 5, d0 = (t & 31) << 1;
  float a0 = 0.f, a1 = 0.f;
  for (int ci = 0; ci < nct; ci++){
    int kb = ci << 8;
    #pragma unroll
    for (int jj = 0; jj < 8; jj++)
      u_s[m16][slot + 32*jj] = sreg[ci*8 + jj];
    if (t < 256){
      int k = kb + t;                                // <= 1023, valid read
      int kpv = kpos_g[b*SEQ + k];
      int rd = qp - kpv; rd = rd > 128 ? 128 : (rd < 0 ? 0 : rd);
      rels_c[t] = rd;
    }
    __syncthreads();
    #pragma unroll
    for (int jj = 0; jj < 8; jj++){
      int j = slot + 32*jj;
      float a = 0.f;
      #pragma unroll
      for (int m = 0; m < 16; m++) a += u_s[m][j] * wpost_s[m][m16];
      w2_s[m16][j] = a;
    }
    __syncthreads();
    int jmax = nk - kb; jmax = jmax > 256 ? 256 : jmax;
    const float* vb = vw + ((size_t)(b*SEQ + kb))*1024 + nn*64 + d0;
    #pragma unroll 4
    for (int j = 0; j < jmax; j++){
      float w = w2_s[nn][j];
      float2 pv = *(const float2*)(vb + (size_t)j*1024);
      unsigned int rp = *(const unsigned int*)&relvb_s[rels_c[j]][d0];
      a0 += w * (pv.x + bflo(rp));
      a1 += w * (pv.y + bfhi(rp));
    }
    __syncthreads();
  }
  float2 res; res.x = a0; res.y = a1;
  *(float2*)(ctx + browq*1024 + nn*64 + d0) = res;
}

extern "C" void kernel_launch(void* const* d_in, const int* in_sizes, int n_in,
                              void* d_out, int out_size, void* d_ws, size_t ws_size,
                              hipStream_t stream)
{
  int ip = -1;
  for (int i = 0; i < n_in; i++){
    if (in_sizes[i] == 2048){ ip = i; break; }
  }
  if (ip < 0) ip = 4;

  const float* query = (const float*)d_in[0];
  const float* key   = (const float*)d_in[1];
  const float* value = (const float*)d_in[2];
  const int* qpos = (const int*)d_in[ip];
  const int* kpos = (const int*)d_in[ip + 1];
  const float* Wq    = (const float*)d_in[ip + 2];
  const float* bq    = (const float*)d_in[ip + 3];
  const float* Wk    = (const float*)d_in[ip + 4];
  const float* bk    = (const float*)d_in[ip + 5];
  const float* Wv    = (const float*)d_in[ip + 6];
  const float* b_v   = (const float*)d_in[ip + 7];
  const float* Wo    = (const float*)d_in[ip + 8];
  const float* bo    = (const float*)d_in[ip + 9];
  const float* relk  = (const float*)d_in[ip + 10];
  const float* relv  = (const float*)d_in[ip + 11];
  const float* wpre  = (const float*)d_in[ip + 12];
  const float* wpost = (const float*)d_in[ip + 13];

  char* ws = (char*)d_ws;
  float* rope = (float*)ws;                                   // 512 KB
  float* q_ws = (float*)(ws + 524288);                        // 8 MB each (fp32)
  float* k_ws = (float*)(ws + 524288 + 8388608);
  float* v_ws = (float*)(ws + 524288 + 2*8388608);
  float* ctx  = (float*)(ws + 524288 + 3*8388608);

  hipLaunchKernelGGL(rope_table_kernel, dim3(256), dim3(256), 0, stream, rope);
  dim3 gg(16, 32);
  hipLaunchKernelGGL(gemm_kernel, gg, dim3(256), 0, stream, query, Wq, bq, q_ws, rope, qpos, 1);
  hipLaunchKernelGGL(gemm_kernel, gg, dim3(256), 0, stream, key,   Wk, bk, k_ws, rope, kpos, 1);
  hipLaunchKernelGGL(gemm_kernel, gg, dim3(256), 0, stream, value, Wv, b_v, v_ws, rope, qpos, 0);
  hipLaunchKernelGGL(attn_kernel, dim3(2048), dim3(512), 0, stream,
                     q_ws, k_ws, v_ws, relk, relv, wpre, wpost, qpos, kpos, ctx);
  hipLaunchKernelGGL(gemm_kernel, gg, dim3(256), 0, stream, ctx, Wo, bo,
                     (float*)d_out, rope, qpos, 0);
}

// Round 5
// 1043.717 us; speedup vs baseline: 2.3782x; 2.3782x over previous
//
#include <hip/hip_runtime.h>

#define SEQ 1024
#define NHEAD 16
#define DHEAD 64

typedef short v8s __attribute__((ext_vector_type(8)));
typedef float v4f __attribute__((ext_vector_type(4)));

__device__ __forceinline__ short f2bfs(float f){
  unsigned int u = __float_as_uint(f);
  u += 0x7fffu + ((u >> 16) & 1u);
  return (short)(u >> 16);
}

// ---------------- RoPE cos/sin table: rope[pos*64 + i]=cos, [pos*64+32+i]=sin ----------------
__global__ void rope_table_kernel(float* __restrict__ rope){
  int idx = blockIdx.x * 256 + threadIdx.x;
  if (idx >= 2048 * 32) return;
  int pos = idx >> 5, i = idx & 31;
  double freq = pow(10000.0, -(double)i / 32.0);
  double a = (double)pos * freq;
  rope[pos * 64 + i]      = (float)cos(a);
  rope[pos * 64 + 32 + i] = (float)sin(a);
}

// ---- MFMA GEMM: out[M=2048,N=1024] = A[2048,1024] @ W[1024,1024]^T + bias (+RoPE if mode) ----
// 64x128 block tile, 256 threads = 4 waves (2x2), BK=32, bf16 MFMA, fp32 accumulate.
__global__ __launch_bounds__(256) void gemm_kernel(
    const float* __restrict__ A, const float* __restrict__ W,
    const float* __restrict__ bias, float* __restrict__ out,
    const float* __restrict__ rope, const int* __restrict__ pos_ids, int mode)
{
  __shared__ short As[64][40];    // bf16 bits; stride 40 => <=2-way bank alias (free)
  __shared__ short Ws[128][40];
  __shared__ float Cs[64][132];

  int t = threadIdx.x;
  int lane = t & 63, wave = t >> 6;
  int l15 = lane & 15, quad = lane >> 4;
  int wm = wave >> 1, wn = wave & 1;     // wave tile: rows wm*32.., cols wn*64..
  int row0 = blockIdx.y << 6;
  int col0 = blockIdx.x << 7;

  v4f acc[2][4];
  #pragma unroll
  for (int i = 0; i < 2; i++)
    #pragma unroll
    for (int j = 0; j < 4; j++)
      acc[i][j] = (v4f){0.f, 0.f, 0.f, 0.f};

  int ar = t >> 2, ac = (t & 3) * 8;     // A-stage: 64 rows x 32 cols, 8 floats/thread
  int wr = t >> 1, wc = (t & 1) * 16;    // W-stage: 128 rows x 32 cols, 16 floats/thread
  const float* apb = A + (size_t)(row0 + ar)*1024 + ac;
  const float* wpb = W + (size_t)(col0 + wr)*1024 + wc;

  for (int kt = 0; kt < 1024; kt += 32){
    const float* ap = apb + kt;
    float4 a0 = *(const float4*)ap, a1 = *(const float4*)(ap + 4);
    v8s av = { f2bfs(a0.x), f2bfs(a0.y), f2bfs(a0.z), f2bfs(a0.w),
               f2bfs(a1.x), f2bfs(a1.y), f2bfs(a1.z), f2bfs(a1.w) };
    *(v8s*)&As[ar][ac] = av;

    const float* wp = wpb + kt;
    float4 w0 = *(const float4*)wp,     w1 = *(const float4*)(wp + 4);
    float4 w2 = *(const float4*)(wp+8), w3 = *(const float4*)(wp + 12);
    v8s wv0 = { f2bfs(w0.x), f2bfs(w0.y), f2bfs(w0.z), f2bfs(w0.w),
                f2bfs(w1.x), f2bfs(w1.y), f2bfs(w1.z), f2bfs(w1.w) };
    v8s wv1 = { f2bfs(w2.x), f2bfs(w2.y), f2bfs(w2.z), f2bfs(w2.w),
                f2bfs(w3.x), f2bfs(w3.y), f2bfs(w3.z), f2bfs(w3.w) };
    *(v8s*)&Ws[wr][wc]     = wv0;
    *(v8s*)&Ws[wr][wc + 8] = wv1;
    __syncthreads();

    v8s af[2], bfq[4];
    #pragma unroll
    for (int i = 0; i < 2; i++) af[i]  = *(v8s*)&As[wm*32 + i*16 + l15][quad*8];
    #pragma unroll
    for (int j = 0; j < 4; j++) bfq[j] = *(v8s*)&Ws[wn*64 + j*16 + l15][quad*8];
    #pragma unroll
    for (int i = 0; i < 2; i++)
      #pragma unroll
      for (int j = 0; j < 4; j++)
        acc[i][j] = __builtin_amdgcn_mfma_f32_16x16x32_bf16(af[i], bfq[j], acc[i][j], 0, 0, 0);
    __syncthreads();
  }

  // acc (C/D layout: col=lane&15, row=quad*4+reg) -> Cs
  #pragma unroll
  for (int i = 0; i < 2; i++)
    #pragma unroll
    for (int j = 0; j < 4; j++)
      #pragma unroll
      for (int r = 0; r < 4; r++)
        Cs[wm*32 + i*16 + quad*4 + r][wn*64 + j*16 + l15] = acc[i][j][r];
  __syncthreads();

  #pragma unroll
  for (int jj = 0; jj < 32; jj++){
    int flat = t + jj*256;           // 64*128 elements
    int r = flat >> 7, c = flat & 127;
    int grow = row0 + r, gcol = col0 + c;
    float x = Cs[r][c] + bias[gcol];
    if (mode){
      float p = Cs[r][c ^ 32] + bias[gcol ^ 32];
      int pos = pos_ids[grow];
      pos = pos < 0 ? 0 : (pos > 2047 ? 2047 : pos);
      int i = c & 31;
      float cs = rope[pos*64 + i];
      float sn = rope[pos*64 + 32 + i];
      x = ((c & 32) == 0) ? (x*cs - p*sn) : (x*cs + p*sn);
    }
    out[(size_t)grow*1024 + gcol] = x;
  }
}

// ---------------- attention (round-3 proven version): one block per (b,q) row ----------------
__global__ __launch_bounds__(512) void attn_kernel(
    const float* __restrict__ qw, const float* __restrict__ kw,
    const float* __restrict__ vw,
    const float* __restrict__ relk, const float* __restrict__ relv,
    const float* __restrict__ wpre_g, const float* __restrict__ wpost_g,
    const int* __restrict__ qpos_g, const int* __restrict__ kpos_g,
    float* __restrict__ ctx)
{
  __shared__ float relv_s[129][68];   // rel_v rows 128..256 (causal => only these used)
  __shared__ float qrel_s[16][132];   // qrel[n][r] = q_n . rel_k[128+r]
  __shared__ float qrow_s[16][68];
  __shared__ float ub1[16][36];
  __shared__ float ub2[16][36];
  __shared__ float red[32][16];
  __shared__ float wpre_s[16][17];
  __shared__ float wpost_s[16][17];
  __shared__ int   rels[32];
  __shared__ float mrow[16];
  __shared__ float invl[16];

  int t = threadIdx.x;
  int bid = blockIdx.x;
  int b = bid & 1;
  int q = (SEQ - 1) - (bid >> 1);   // longest rows dispatched first
  size_t browq = (size_t)(b*SEQ + q);

  for (int f = t; f < 1024; f += 512)
    qrow_s[f >> 6][f & 63] = qw[browq*1024 + f];
  if (t < 256) wpre_s[t >> 4][t & 15] = wpre_g[t];
  else { int u = t - 256; wpost_s[u >> 4][u & 15] = wpost_g[u]; }
  for (int e = t; e < 129*64; e += 512){
    int r = e >> 6, d = e & 63;
    relv_s[r][d] = relv[(size_t)(128 + r)*64 + d];
  }
  __syncthreads();

  int m16 = t & 15, kj = t >> 4;  // kj in 0..31
  for (int r = kj; r < 129; r += 32){
    const float* rk = relk + (size_t)(128 + r)*64;
    float s = 0.f;
    #pragma unroll
    for (int d4 = 0; d4 < 64; d4 += 4){
      float4 pv = *(const float4*)(rk + d4);
      float4 qv = *(const float4*)&qrow_s[m16][d4];
      s += qv.x*pv.x + qv.y*pv.y + qv.z*pv.z + qv.w*pv.w;
    }
    qrel_s[m16][r] = s;
  }
  int qp = qpos_g[b*SEQ + q];
  __syncthreads();

  int nk = q + 1;
  int nct = (nk + 31) >> 5;
  float sreg[32];
  #pragma unroll
  for (int i = 0; i < 32; i++) sreg[i] = -1e30f;

  for (int ci = 0; ci < nct; ci++){
    int k = (ci << 5) + kj;
    float uval = 0.f;
    if (k < nk){
      const float* kv = kw + ((size_t)(b*SEQ + k))*1024 + m16*64;
      float s = 0.f;
      #pragma unroll
      for (int d4 = 0; d4 < 64; d4 += 4){
        float4 pv = *(const float4*)(kv + d4);
        float4 qv = *(const float4*)&qrow_s[m16][d4];
        s += qv.x*pv.x + qv.y*pv.y + qv.z*pv.z + qv.w*pv.w;
      }
      int kp = kpos_g[b*SEQ + k];
      int rd = qp - kp; rd = rd > 128 ? 128 : (rd < 0 ? 0 : rd);
      uval = (s + qrel_s[m16][rd]) * 0.125f;
    }
    ub1[m16][kj] = uval;
    __syncthreads();
    if (k < nk){
      float acc2 = 0.f;
      #pragma unroll
      for (int n = 0; n < 16; n++) acc2 += ub1[n][kj] * wpre_s[n][m16];
      sreg[ci] = acc2;
    }
    __syncthreads();
  }

  float loc = -1e30f;
  for (int i = 0; i < nct; i++) loc = fmaxf(loc, sreg[i]);
  red[kj][m16] = loc;
  __syncthreads();
  if (t < 16){
    float v = -1e30f;
    #pragma unroll
    for (int s2 = 0; s2 < 32; s2++) v = fmaxf(v, red[s2][t]);
    mrow[t] = v;
  }
  __syncthreads();
  float mm = mrow[m16];
  float ls = 0.f;
  for (int i = 0; i < nct; i++){
    float arg = fmaxf(sreg[i] - mm, -80.f);
    float p = __expf(arg);
    sreg[i] = p;
    ls += p;
  }
  red[kj][m16] = ls;
  __syncthreads();
  if (t < 16){
    float v = 0.f;
    #pragma unroll
    for (int s2 = 0; s2 < 32; s2++) v += red[s2][t];
    invl[t] = 1.f / v;
  }
  __syncthreads();
  if (t < 256){ int m = t >> 4, n = t & 15; wpost_s[m][n] *= invl[m]; }
  __syncthreads();

  int nn = t >> 5, d0 = (t & 31) << 1;
  float a0 = 0.f, a1 = 0.f;
  for (int ci = 0; ci < nct; ci++){
    int kb = ci << 5;
    ub1[m16][kj] = sreg[ci];
    if (t < 32){
      int k = kb + t, rd = 0;
      if (k < nk){ int kp = kpos_g[b*SEQ + k]; rd = qp - kp; rd = rd > 128 ? 128 : (rd < 0 ? 0 : rd); }
      rels[t] = rd;
    }
    __syncthreads();
    {
      int k = kb + kj;
      float acc2 = 0.f;
      if (k < nk){
        #pragma unroll
        for (int m = 0; m < 16; m++) acc2 += ub1[m][kj] * wpost_s[m][m16];
      }
      ub2[m16][kj] = acc2;
    }
    __syncthreads();
    int lim = nk - kb; lim = lim > 32 ? 32 : lim;
    const float* vb = vw + ((size_t)(b*SEQ + kb))*1024 + nn*64 + d0;
    for (int j = 0; j < lim; j++){
      float w = ub2[nn][j];
      float2 pv = *(const float2*)(vb + (size_t)j*1024);
      int rd = rels[j];
      a0 += w * (pv.x + relv_s[rd][d0]);
      a1 += w * (pv.y + relv_s[rd][d0 + 1]);
    }
    __syncthreads();
  }
  float2 res; res.x = a0; res.y = a1;
  *(float2*)(ctx + browq*1024 + nn*64 + d0) = res;
}

extern "C" void kernel_launch(void* const* d_in, const int* in_sizes, int n_in,
                              void* d_out, int out_size, void* d_ws, size_t ws_size,
                              hipStream_t stream)
{
  int ip = -1;
  for (int i = 0; i < n_in; i++){
    if (in_sizes[i] == 2048){ ip = i; break; }
  }
  if (ip < 0) ip = 4;

  const float* query = (const float*)d_in[0];
  const float* key   = (const float*)d_in[1];
  const float* value = (const float*)d_in[2];
  const int* qpos = (const int*)d_in[ip];
  const int* kpos = (const int*)d_in[ip + 1];
  const float* Wq    = (const float*)d_in[ip + 2];
  const float* bq    = (const float*)d_in[ip + 3];
  const float* Wk    = (const float*)d_in[ip + 4];
  const float* bk    = (const float*)d_in[ip + 5];
  const float* Wv    = (const float*)d_in[ip + 6];
  const float* b_v   = (const float*)d_in[ip + 7];
  const float* Wo    = (const float*)d_in[ip + 8];
  const float* bo    = (const float*)d_in[ip + 9];
  const float* relk  = (const float*)d_in[ip + 10];
  const float* relv  = (const float*)d_in[ip + 11];
  const float* wpre  = (const float*)d_in[ip + 12];
  const float* wpost = (const float*)d_in[ip + 13];

  char* ws = (char*)d_ws;
  float* rope = (float*)ws;                                   // 512 KB
  float* q_ws = (float*)(ws + 524288);                        // 8 MB each (fp32)
  float* k_ws = (float*)(ws + 524288 + 8388608);
  float* v_ws = (float*)(ws + 524288 + 2*8388608);
  float* ctx  = (float*)(ws + 524288 + 3*8388608);

  hipLaunchKernelGGL(rope_table_kernel, dim3(256), dim3(256), 0, stream, rope);
  dim3 gg(8, 32);   // N/128 x M/64
  hipLaunchKernelGGL(gemm_kernel, gg, dim3(256), 0, stream, query, Wq, bq, q_ws, rope, qpos, 1);
  hipLaunchKernelGGL(gemm_kernel, gg, dim3(256), 0, stream, key,   Wk, bk, k_ws, rope, kpos, 1);
  hipLaunchKernelGGL(gemm_kernel, gg, dim3(256), 0, stream, value, Wv, b_v, v_ws, rope, qpos, 0);
  hipLaunchKernelGGL(attn_kernel, dim3(2048), dim3(512), 0, stream,
                     q_ws, k_ws, v_ws, relk, relv, wpre, wpost, qpos, kpos, ctx);
  hipLaunchKernelGGL(gemm_kernel, gg, dim3(256), 0, stream, ctx, Wo, bo,
                     (float*)d_out, rope, qpos, 0);
}

// Round 7
// 803.204 us; speedup vs baseline: 3.0904x; 1.2994x over previous
//
#include <hip/hip_runtime.h>

#define SEQ 1024
#define NHEAD 16
#define DHEAD 64

typedef short v8s __attribute__((ext_vector_type(8)));
typedef float v4f __attribute__((ext_vector_type(4)));

__device__ __forceinline__ short f2bfs(float f){
  unsigned int u = __float_as_uint(f);
  u += 0x7fffu + ((u >> 16) & 1u);
  return (short)(u >> 16);
}
__device__ __forceinline__ float bfl(short s){
  return __uint_as_float(((unsigned int)(unsigned short)s) << 16);
}

// ---------------- RoPE cos/sin table ----------------
__global__ void rope_table_kernel(float* __restrict__ rope){
  int idx = blockIdx.x * 256 + threadIdx.x;
  if (idx >= 2048 * 32) return;
  int pos = idx >> 5, i = idx & 31;
  double freq = pow(10000.0, -(double)i / 32.0);
  double a = (double)pos * freq;
  rope[pos * 64 + i]      = (float)cos(a);
  rope[pos * 64 + 32 + i] = (float)sin(a);
}

// ---- MFMA GEMM (r5, proven): out[2048,1024] = A @ W^T + bias (+RoPE if mode) ----
__global__ __launch_bounds__(256) void gemm_kernel(
    const float* __restrict__ A, const float* __restrict__ W,
    const float* __restrict__ bias, float* __restrict__ out,
    const float* __restrict__ rope, const int* __restrict__ pos_ids, int mode)
{
  __shared__ short As[64][40];
  __shared__ short Ws[128][40];
  __shared__ float Cs[64][132];

  int t = threadIdx.x;
  int lane = t & 63, wave = t >> 6;
  int l15 = lane & 15, quad = lane >> 4;
  int wm = wave >> 1, wn = wave & 1;
  int row0 = blockIdx.y << 6;
  int col0 = blockIdx.x << 7;

  v4f acc[2][4];
  #pragma unroll
  for (int i = 0; i < 2; i++)
    #pragma unroll
    for (int j = 0; j < 4; j++)
      acc[i][j] = (v4f){0.f, 0.f, 0.f, 0.f};

  int ar = t >> 2, ac = (t & 3) * 8;
  int wr = t >> 1, wc = (t & 1) * 16;
  const float* apb = A + (size_t)(row0 + ar)*1024 + ac;
  const float* wpb = W + (size_t)(col0 + wr)*1024 + wc;

  for (int kt = 0; kt < 1024; kt += 32){
    const float* ap = apb + kt;
    float4 a0 = *(const float4*)ap, a1 = *(const float4*)(ap + 4);
    v8s av = { f2bfs(a0.x), f2bfs(a0.y), f2bfs(a0.z), f2bfs(a0.w),
               f2bfs(a1.x), f2bfs(a1.y), f2bfs(a1.z), f2bfs(a1.w) };
    *(v8s*)&As[ar][ac] = av;

    const float* wp = wpb + kt;
    float4 w0 = *(const float4*)wp,     w1 = *(const float4*)(wp + 4);
    float4 w2 = *(const float4*)(wp+8), w3 = *(const float4*)(wp + 12);
    v8s wv0 = { f2bfs(w0.x), f2bfs(w0.y), f2bfs(w0.z), f2bfs(w0.w),
                f2bfs(w1.x), f2bfs(w1.y), f2bfs(w1.z), f2bfs(w1.w) };
    v8s wv1 = { f2bfs(w2.x), f2bfs(w2.y), f2bfs(w2.z), f2bfs(w2.w),
                f2bfs(w3.x), f2bfs(w3.y), f2bfs(w3.z), f2bfs(w3.w) };
    *(v8s*)&Ws[wr][wc]     = wv0;
    *(v8s*)&Ws[wr][wc + 8] = wv1;
    __syncthreads();

    v8s af[2], bfq[4];
    #pragma unroll
    for (int i = 0; i < 2; i++) af[i]  = *(v8s*)&As[wm*32 + i*16 + l15][quad*8];
    #pragma unroll
    for (int j = 0; j < 4; j++) bfq[j] = *(v8s*)&Ws[wn*64 + j*16 + l15][quad*8];
    #pragma unroll
    for (int i = 0; i < 2; i++)
      #pragma unroll
      for (int j = 0; j < 4; j++)
        acc[i][j] = __builtin_amdgcn_mfma_f32_16x16x32_bf16(af[i], bfq[j], acc[i][j], 0, 0, 0);
    __syncthreads();
  }

  #pragma unroll
  for (int i = 0; i < 2; i++)
    #pragma unroll
    for (int j = 0; j < 4; j++)
      #pragma unroll
      for (int r = 0; r < 4; r++)
        Cs[wm*32 + i*16 + quad*4 + r][wn*64 + j*16 + l15] = acc[i][j][r];
  __syncthreads();

  #pragma unroll
  for (int jj = 0; jj < 32; jj++){
    int flat = t + jj*256;
    int r = flat >> 7, c = flat & 127;
    int grow = row0 + r, gcol = col0 + c;
    float x = Cs[r][c] + bias[gcol];
    if (mode){
      float p = Cs[r][c ^ 32] + bias[gcol ^ 32];
      int pos = pos_ids[grow];
      pos = pos < 0 ? 0 : (pos > 2047 ? 2047 : pos);
      int i = c & 31;
      float cs = rope[pos*64 + i];
      float sn = rope[pos*64 + 32 + i];
      x = ((c & 32) == 0) ? (x*cs - p*sn) : (x*cs + p*sn);
    }
    out[(size_t)grow*1024 + gcol] = x;
  }
}

// ---------- MFMA two-pass flash attention; talking heads applied EXACTLY ----------
// Block = (b, 16-row q-tile). 1024 threads = 16 waves; wave w = q-row owner w AND head owner w.
// Pass 1: (M,l) per (head m, q-row). Pass 2: recompute scores, exact attn, post-mix
// (MFMA, 16x16), then PV pairs mixed-attn head n with HEAD n's V (the r6 bug fix).
__global__ __launch_bounds__(1024) void attn_kernel(
    const float* __restrict__ qw, const float* __restrict__ kw,
    const float* __restrict__ vw,
    const float* __restrict__ relk, const float* __restrict__ relv,
    const float* __restrict__ wpre_g, const float* __restrict__ wpost_g,
    float* __restrict__ ctx)
{
  __shared__ __align__(16) char pool[142088];
  short (*U_t)[40]      = (short(*)[40])(pool);               // [512=(i,j)][col: head] raw scores / exact attn (At)
  short (*W_l)[16][48]  = (short(*)[16][48])(pool + 40960);   // qrel window, per-wave private rows
  short (*Pp)[16][40]   = (short(*)[16][40])(pool + 65536);   // post-mixed attn [n][i][j]
  short (*Tt)[16][72]   = (short(*)[16][72])(pool + 86016);   // skewed post-mixed attn [n][i][p]
  short (*relv_s)[66]   = (short(*)[66])(pool + 122880);      // relv rows 128..256 bf16
  float (*M_l)[17]      = (float(*)[17])(pool + 139912);      // [m][i] row max
  float (*il_l)[17]     = (float(*)[17])(pool + 141000);      // [m][i] 1/l

  int t = threadIdx.x;
  int h = t >> 6, lane = t & 63;
  int l15 = lane & 15, quad = lane >> 4;
  int b = blockIdx.x & 1;
  int q0 = (63 - (blockIdx.x >> 1)) << 4;   // descending q-tiles (longest first)

  { // zero U_t (cols>=16 stay 0) and Tt (unwritten skew slots stay 0)
    int* p0 = (int*)pool;
    for (int e = t; e < 10240; e += 1024) p0[e] = 0;
    int* p1 = (int*)(pool + 86016);
    for (int e = t; e < 9216; e += 1024) p1[e] = 0;
  }
  for (int e = t; e < 129*64; e += 1024){
    relv_s[e >> 6][e & 63] = f2bfs(relv[(size_t)(128 + (e >> 6))*64 + (e & 63)]);
  }

  // A-frags: awp = wpre^T (pre-mix), awq = wpost^T (post-mix); contraction padded 16->32 w/ zeros
  v8s awp, awq;
  #pragma unroll
  for (int jj = 0; jj < 8; jj++){
    int n = quad*8 + jj;
    awp[jj] = (n < 16) ? f2bfs(wpre_g[n*16 + l15])  : (short)0;
    awq[jj] = (n < 16) ? f2bfs(wpost_g[n*16 + l15]) : (short)0;
  }
  // Q A-frags for head h (rows q0+l15)
  v8s aq[2];
  {
    const float* qb = qw + ((size_t)(b*SEQ + q0 + l15))*1024 + h*64;
    #pragma unroll
    for (int c = 0; c < 2; c++){
      float4 x = *(const float4*)(qb + c*32 + quad*8);
      float4 y = *(const float4*)(qb + c*32 + quad*8 + 4);
      v8s v; v[0]=f2bfs(x.x); v[1]=f2bfs(x.y); v[2]=f2bfs(x.z); v[3]=f2bfs(x.w);
             v[4]=f2bfs(y.x); v[5]=f2bfs(y.y); v[6]=f2bfs(y.z); v[7]=f2bfs(y.w);
      aq[c] = v;
    }
  }
  __syncthreads();

  int nkt = (q0 + 47) >> 5;

  // ================= PASS 1: per (head m, q-row h) running max & sum =================
  float M_st[4] = {-1e30f, -1e30f, -1e30f, -1e30f};
  float l_st[4] = {0.f, 0.f, 0.f, 0.f};

  for (int ci = 0; ci < nkt; ci++){
    int k0 = ci << 5;
    int r_lo = q0 - k0 - 31;

    v4f cqk[2];
    #pragma unroll
    for (int ct = 0; ct < 2; ct++){
      const float* kb = kw + ((size_t)(b*SEQ + k0 + ct*16 + l15))*1024 + h*64;
      v4f acc = (v4f){0.f,0.f,0.f,0.f};
      #pragma unroll
      for (int c = 0; c < 2; c++){
        float4 x = *(const float4*)(kb + c*32 + quad*8);
        float4 y = *(const float4*)(kb + c*32 + quad*8 + 4);
        v8s kv; kv[0]=f2bfs(x.x); kv[1]=f2bfs(x.y); kv[2]=f2bfs(x.z); kv[3]=f2bfs(x.w);
                kv[4]=f2bfs(y.x); kv[5]=f2bfs(y.y); kv[6]=f2bfs(y.z); kv[7]=f2bfs(y.w);
        acc = __builtin_amdgcn_mfma_f32_16x16x32_bf16(aq[c], kv, acc, 0, 0, 0);
      }
      cqk[ct] = acc;
    }
    #pragma unroll
    for (int pt = 0; pt < 3; pt++){
      int rr = r_lo + pt*16 + l15; rr = rr < 0 ? 0 : (rr > 128 ? 128 : rr);
      const float* rkb = relk + (size_t)(128 + rr)*64;
      v4f acc = (v4f){0.f,0.f,0.f,0.f};
      #pragma unroll
      for (int c = 0; c < 2; c++){
        float4 x = *(const float4*)(rkb + c*32 + quad*8);
        float4 y = *(const float4*)(rkb + c*32 + quad*8 + 4);
        v8s rv; rv[0]=f2bfs(x.x); rv[1]=f2bfs(x.y); rv[2]=f2bfs(x.z); rv[3]=f2bfs(x.w);
                rv[4]=f2bfs(y.x); rv[5]=f2bfs(y.y); rv[6]=f2bfs(y.z); rv[7]=f2bfs(y.w);
        acc = __builtin_amdgcn_mfma_f32_16x16x32_bf16(aq[c], rv, acc, 0, 0, 0);
      }
      #pragma unroll
      for (int reg = 0; reg < 4; reg++)
        W_l[h][quad*4 + reg][pt*16 + l15] = f2bfs(acc[reg]);
    }
    #pragma unroll
    for (int ct = 0; ct < 2; ct++)
      #pragma unroll
      for (int reg = 0; reg < 4; reg++){
        int i = quad*4 + reg, j = ct*16 + l15;
        float wv = bfl(W_l[h][i][i - j + 31]);
        U_t[i*32 + j][h] = f2bfs((cqk[ct][reg] + wv) * 0.125f);
      }
    __syncthreads();   // B1: U ready

    v4f cs[2];
    #pragma unroll
    for (int ct = 0; ct < 2; ct++){
      v8s bu = *(v8s*)&U_t[h*32 + ct*16 + l15][quad*8];
      cs[ct] = __builtin_amdgcn_mfma_f32_16x16x32_bf16(awp, bu, (v4f){0.f,0.f,0.f,0.f}, 0, 0, 0);
    }
    bool v0 = (k0 + l15)      <= (q0 + h);
    bool v1 = (k0 + 16 + l15) <= (q0 + h);
    #pragma unroll
    for (int reg = 0; reg < 4; reg++){
      float s0 = v0 ? cs[0][reg] : -1e4f;
      float s1 = v1 ? cs[1][reg] : -1e4f;
      float mx = fmaxf(s0, s1);
      mx = fmaxf(mx, __shfl_xor(mx, 1, 64));
      mx = fmaxf(mx, __shfl_xor(mx, 2, 64));
      mx = fmaxf(mx, __shfl_xor(mx, 4, 64));
      mx = fmaxf(mx, __shfl_xor(mx, 8, 64));
      float Mn = fmaxf(M_st[reg], mx);
      float al = __expf(fmaxf(M_st[reg] - Mn, -100.f));
      M_st[reg] = Mn;
      float p0 = v0 ? __expf(s0 - Mn) : 0.f;
      float p1 = v1 ? __expf(s1 - Mn) : 0.f;
      float sm = p0 + p1;
      sm += __shfl_xor(sm, 1, 64);
      sm += __shfl_xor(sm, 2, 64);
      sm += __shfl_xor(sm, 4, 64);
      sm += __shfl_xor(sm, 8, 64);
      l_st[reg] = l_st[reg]*al + sm;
    }
    __syncthreads();   // B2: U consumed, re-stageable
  }
  if (l15 == 0){
    #pragma unroll
    for (int reg = 0; reg < 4; reg++){
      M_l[quad*4 + reg][h]  = M_st[reg];
      il_l[quad*4 + reg][h] = 1.f / l_st[reg];
    }
  }
  __syncthreads();

  // ================= PASS 2: exact attn, post-mix, PV + rel_v =================
  float Mh[4], ilh[4];
  #pragma unroll
  for (int reg = 0; reg < 4; reg++){
    Mh[reg]  = M_l[quad*4 + reg][h];
    ilh[reg] = il_l[quad*4 + reg][h];
  }
  v4f o_acc[4];
  #pragma unroll
  for (int dt = 0; dt < 4; dt++) o_acc[dt] = (v4f){0.f,0.f,0.f,0.f};

  for (int ci = 0; ci < nkt; ci++){
    int k0 = ci << 5;
    int r_lo = q0 - k0 - 31;

    // --- recompute raw mixed-input scores, stage U_t (identical to pass 1) ---
    v4f cqk[2];
    #pragma unroll
    for (int ct = 0; ct < 2; ct++){
      const float* kb = kw + ((size_t)(b*SEQ + k0 + ct*16 + l15))*1024 + h*64;
      v4f acc = (v4f){0.f,0.f,0.f,0.f};
      #pragma unroll
      for (int c = 0; c < 2; c++){
        float4 x = *(const float4*)(kb + c*32 + quad*8);
        float4 y = *(const float4*)(kb + c*32 + quad*8 + 4);
        v8s kv; kv[0]=f2bfs(x.x); kv[1]=f2bfs(x.y); kv[2]=f2bfs(x.z); kv[3]=f2bfs(x.w);
                kv[4]=f2bfs(y.x); kv[5]=f2bfs(y.y); kv[6]=f2bfs(y.z); kv[7]=f2bfs(y.w);
        acc = __builtin_amdgcn_mfma_f32_16x16x32_bf16(aq[c], kv, acc, 0, 0, 0);
      }
      cqk[ct] = acc;
    }
    #pragma unroll
    for (int pt = 0; pt < 3; pt++){
      int rr = r_lo + pt*16 + l15; rr = rr < 0 ? 0 : (rr > 128 ? 128 : rr);
      const float* rkb = relk + (size_t)(128 + rr)*64;
      v4f acc = (v4f){0.f,0.f,0.f,0.f};
      #pragma unroll
      for (int c = 0; c < 2; c++){
        float4 x = *(const float4*)(rkb + c*32 + quad*8);
        float4 y = *(const float4*)(rkb + c*32 + quad*8 + 4);
        v8s rv; rv[0]=f2bfs(x.x); rv[1]=f2bfs(x.y); rv[2]=f2bfs(x.z); rv[3]=f2bfs(x.w);
                rv[4]=f2bfs(y.x); rv[5]=f2bfs(y.y); rv[6]=f2bfs(y.z); rv[7]=f2bfs(y.w);
        acc = __builtin_amdgcn_mfma_f32_16x16x32_bf16(aq[c], rv, acc, 0, 0, 0);
      }
      #pragma unroll
      for (int reg = 0; reg < 4; reg++)
        W_l[h][quad*4 + reg][pt*16 + l15] = f2bfs(acc[reg]);
    }
    #pragma unroll
    for (int ct = 0; ct < 2; ct++)
      #pragma unroll
      for (int reg = 0; reg < 4; reg++){
        int i = quad*4 + reg, j = ct*16 + l15;
        float wv = bfl(W_l[h][i][i - j + 31]);
        U_t[i*32 + j][h] = f2bfs((cqk[ct][reg] + wv) * 0.125f);
      }
    __syncthreads();   // B1

    // --- pre-mix + exact attn ---
    v4f cs[2];
    #pragma unroll
    for (int ct = 0; ct < 2; ct++){
      v8s bu = *(v8s*)&U_t[h*32 + ct*16 + l15][quad*8];
      cs[ct] = __builtin_amdgcn_mfma_f32_16x16x32_bf16(awp, bu, (v4f){0.f,0.f,0.f,0.f}, 0, 0, 0);
    }
    bool v0 = (k0 + l15)      <= (q0 + h);
    bool v1 = (k0 + 16 + l15) <= (q0 + h);
    float pr[2][4];
    #pragma unroll
    for (int reg = 0; reg < 4; reg++){
      pr[0][reg] = v0 ? __expf(cs[0][reg] - Mh[reg]) * ilh[reg] : 0.f;
      pr[1][reg] = v1 ? __expf(cs[1][reg] - Mh[reg]) * ilh[reg] : 0.f;
    }
    __syncthreads();   // B2: mix readers done -> overwrite U_t with At

    #pragma unroll
    for (int ct = 0; ct < 2; ct++)
      #pragma unroll
      for (int reg = 0; reg < 4; reg++)
        U_t[h*32 + ct*16 + l15][quad*4 + reg] = f2bfs(pr[ct][reg]);   // At[(i=h,j)][m]
    __syncthreads();   // B3: At ready

    // --- post-mix: attn_post[n][i=h][j] = sum_m wpost[m][n] attn[m][i][j] ---
    #pragma unroll
    for (int ct = 0; ct < 2; ct++){
      v8s bu = *(v8s*)&U_t[h*32 + ct*16 + l15][quad*8];
      v4f cp = __builtin_amdgcn_mfma_f32_16x16x32_bf16(awq, bu, (v4f){0.f,0.f,0.f,0.f}, 0, 0, 0);
      #pragma unroll
      for (int reg = 0; reg < 4; reg++){
        int n = quad*4 + reg, j = ct*16 + l15;
        short pb = f2bfs(cp[reg]);
        Pp[n][h][j] = pb;
        Tt[n][h][h + 31 - j] = pb;
      }
    }
    __syncthreads();   // B4: Pp/Tt ready

    // --- PV with HEAD h's V (the fix) + skewed rel_v ---
    v8s ap = *(v8s*)&Pp[h][l15][quad*8];
    const float* vb = vw + ((size_t)(b*SEQ + k0 + quad*8))*1024 + h*64;
    #pragma unroll
    for (int dt = 0; dt < 4; dt++){
      v8s bv;
      #pragma unroll
      for (int jj = 0; jj < 8; jj++)
        bv[jj] = f2bfs(vb[(size_t)jj*1024 + dt*16 + l15]);
      o_acc[dt] = __builtin_amdgcn_mfma_f32_16x16x32_bf16(ap, bv, o_acc[dt], 0, 0, 0);
    }
    #pragma unroll
    for (int ch = 0; ch < 2; ch++){
      v8s at = *(v8s*)&Tt[h][l15][ch*32 + quad*8];
      #pragma unroll
      for (int dt = 0; dt < 4; dt++){
        v8s br;
        #pragma unroll
        for (int jj = 0; jj < 8; jj++){
          int rr = r_lo + ch*32 + quad*8 + jj;
          rr = rr < 0 ? 0 : (rr > 128 ? 128 : rr);
          br[jj] = relv_s[rr][dt*16 + l15];
        }
        o_acc[dt] = __builtin_amdgcn_mfma_f32_16x16x32_bf16(at, br, o_acc[dt], 0, 0, 0);
      }
    }
  }

  // ---- epilogue: o_acc is final (normalized, post-mixed); write head h ----
  #pragma unroll
  for (int dt = 0; dt < 4; dt++)
    #pragma unroll
    for (int reg = 0; reg < 4; reg++)
      ctx[((size_t)(b*SEQ + q0 + quad*4 + reg))*1024 + h*64 + dt*16 + l15] = o_acc[dt][reg];
}

extern "C" void kernel_launch(void* const* d_in, const int* in_sizes, int n_in,
                              void* d_out, int out_size, void* d_ws, size_t ws_size,
                              hipStream_t stream)
{
  int ip = -1;
  for (int i = 0; i < n_in; i++){
    if (in_sizes[i] == 2048){ ip = i; break; }
  }
  if (ip < 0) ip = 4;

  const float* query = (const float*)d_in[0];
  const float* key   = (const float*)d_in[1];
  const float* value = (const float*)d_in[2];
  const int* qpos = (const int*)d_in[ip];
  const int* kpos = (const int*)d_in[ip + 1];
  const float* Wq    = (const float*)d_in[ip + 2];
  const float* bq    = (const float*)d_in[ip + 3];
  const float* Wk    = (const float*)d_in[ip + 4];
  const float* bk    = (const float*)d_in[ip + 5];
  const float* Wv    = (const float*)d_in[ip + 6];
  const float* b_v   = (const float*)d_in[ip + 7];
  const float* Wo    = (const float*)d_in[ip + 8];
  const float* bo    = (const float*)d_in[ip + 9];
  const float* relk  = (const float*)d_in[ip + 10];
  const float* relv  = (const float*)d_in[ip + 11];
  const float* wpre  = (const float*)d_in[ip + 12];
  const float* wpost = (const float*)d_in[ip + 13];

  char* ws = (char*)d_ws;
  float* rope = (float*)ws;                                   // 512 KB
  float* q_ws = (float*)(ws + 524288);                        // 8 MB each (fp32)
  float* k_ws = (float*)(ws + 524288 + 8388608);
  float* v_ws = (float*)(ws + 524288 + 2*8388608);
  float* ctx  = (float*)(ws + 524288 + 3*8388608);

  hipLaunchKernelGGL(rope_table_kernel, dim3(256), dim3(256), 0, stream, rope);
  dim3 gg(8, 32);
  hipLaunchKernelGGL(gemm_kernel, gg, dim3(256), 0, stream, query, Wq, bq, q_ws, rope, qpos, 1);
  hipLaunchKernelGGL(gemm_kernel, gg, dim3(256), 0, stream, key,   Wk, bk, k_ws, rope, kpos, 1);
  hipLaunchKernelGGL(gemm_kernel, gg, dim3(256), 0, stream, value, Wv, b_v, v_ws, rope, qpos, 0);
  hipLaunchKernelGGL(attn_kernel, dim3(128), dim3(1024), 0, stream,
                     q_ws, k_ws, v_ws, relk, relv, wpre, wpost, ctx);
  hipLaunchKernelGGL(gemm_kernel, gg, dim3(256), 0, stream, ctx, Wo, bo,
                     (float*)d_out, rope, qpos, 0);
}

// Round 8
// 655.441 us; speedup vs baseline: 3.7870x; 1.2254x over previous
//
#include <hip/hip_runtime.h>

#define SEQ 1024
#define NHEAD 16
#define DHEAD 64

typedef short v8s __attribute__((ext_vector_type(8)));
typedef float v4f __attribute__((ext_vector_type(4)));

__device__ __forceinline__ short f2bfs(float f){
  unsigned int u = __float_as_uint(f);
  u += 0x7fffu + ((u >> 16) & 1u);
  return (short)(u >> 16);
}
__device__ __forceinline__ float bfl(short s){
  return __uint_as_float(((unsigned int)(unsigned short)s) << 16);
}

// ---------------- RoPE cos/sin table ----------------
__global__ void rope_table_kernel(float* __restrict__ rope){
  int idx = blockIdx.x * 256 + threadIdx.x;
  if (idx >= 2048 * 32) return;
  int pos = idx >> 5, i = idx & 31;
  double freq = pow(10000.0, -(double)i / 32.0);
  double a = (double)pos * freq;
  rope[pos * 64 + i]      = (float)cos(a);
  rope[pos * 64 + 32 + i] = (float)sin(a);
}

// ---- MFMA GEMM: C[2048,1024] = A @ W^T + bias.
// mode 0: fp32 out. mode 1: bf16 out + RoPE (Q,K). mode 2: bf16 TRANSPOSED out
// vT[b*1024 + h*64+d][seq] (V, for contiguous PV B-frags in attention).
__global__ __launch_bounds__(256) void gemm_kernel(
    const float* __restrict__ A, const float* __restrict__ W,
    const float* __restrict__ bias, void* __restrict__ outv,
    const float* __restrict__ rope, const int* __restrict__ pos_ids, int mode)
{
  __shared__ short As[64][40];
  __shared__ short Ws[128][40];
  __shared__ float Cs[64][133];   // stride 133 (coprime w/ 32) for mode-2 column reads

  int t = threadIdx.x;
  int lane = t & 63, wave = t >> 6;
  int l15 = lane & 15, quad = lane >> 4;
  int wm = wave >> 1, wn = wave & 1;
  int row0 = blockIdx.y << 6;
  int col0 = blockIdx.x << 7;

  v4f acc[2][4];
  #pragma unroll
  for (int i = 0; i < 2; i++)
    #pragma unroll
    for (int j = 0; j < 4; j++)
      acc[i][j] = (v4f){0.f, 0.f, 0.f, 0.f};

  int ar = t >> 2, ac = (t & 3) * 8;
  int wr = t >> 1, wc = (t & 1) * 16;
  const float* apb = A + (size_t)(row0 + ar)*1024 + ac;
  const float* wpb = W + (size_t)(col0 + wr)*1024 + wc;

  for (int kt = 0; kt < 1024; kt += 32){
    const float* ap = apb + kt;
    float4 a0 = *(const float4*)ap, a1 = *(const float4*)(ap + 4);
    v8s av = { f2bfs(a0.x), f2bfs(a0.y), f2bfs(a0.z), f2bfs(a0.w),
               f2bfs(a1.x), f2bfs(a1.y), f2bfs(a1.z), f2bfs(a1.w) };
    *(v8s*)&As[ar][ac] = av;

    const float* wp = wpb + kt;
    float4 w0 = *(const float4*)wp,     w1 = *(const float4*)(wp + 4);
    float4 w2 = *(const float4*)(wp+8), w3 = *(const float4*)(wp + 12);
    v8s wv0 = { f2bfs(w0.x), f2bfs(w0.y), f2bfs(w0.z), f2bfs(w0.w),
                f2bfs(w1.x), f2bfs(w1.y), f2bfs(w1.z), f2bfs(w1.w) };
    v8s wv1 = { f2bfs(w2.x), f2bfs(w2.y), f2bfs(w2.z), f2bfs(w2.w),
                f2bfs(w3.x), f2bfs(w3.y), f2bfs(w3.z), f2bfs(w3.w) };
    *(v8s*)&Ws[wr][wc]     = wv0;
    *(v8s*)&Ws[wr][wc + 8] = wv1;
    __syncthreads();

    v8s af[2], bfq[4];
    #pragma unroll
    for (int i = 0; i < 2; i++) af[i]  = *(v8s*)&As[wm*32 + i*16 + l15][quad*8];
    #pragma unroll
    for (int j = 0; j < 4; j++) bfq[j] = *(v8s*)&Ws[wn*64 + j*16 + l15][quad*8];
    #pragma unroll
    for (int i = 0; i < 2; i++)
      #pragma unroll
      for (int j = 0; j < 4; j++)
        acc[i][j] = __builtin_amdgcn_mfma_f32_16x16x32_bf16(af[i], bfq[j], acc[i][j], 0, 0, 0);
    __syncthreads();
  }

  #pragma unroll
  for (int i = 0; i < 2; i++)
    #pragma unroll
    for (int j = 0; j < 4; j++)
      #pragma unroll
      for (int r = 0; r < 4; r++)
        Cs[wm*32 + i*16 + quad*4 + r][wn*64 + j*16 + l15] = acc[i][j][r];
  __syncthreads();

  if (mode == 2){
    // bf16 transposed: vT[(b*1024 + gcol)][s]; 64 consecutive lanes -> consecutive s
    unsigned short* o16 = (unsigned short*)outv;
    #pragma unroll
    for (int jj = 0; jj < 32; jj++){
      int flat = t + jj*256;
      int sl = flat & 63, c = flat >> 6;
      int grow = row0 + sl, gcol = col0 + c;
      float x = Cs[sl][c] + bias[gcol];
      int bb = grow >> 10, s = grow & 1023;
      o16[((size_t)(bb*1024 + gcol))*1024 + s] = (unsigned short)f2bfs(x);
    }
  } else if (mode == 1){
    unsigned short* o16 = (unsigned short*)outv;
    #pragma unroll
    for (int jj = 0; jj < 32; jj++){
      int flat = t + jj*256;
      int r = flat >> 7, c = flat & 127;
      int grow = row0 + r, gcol = col0 + c;
      float x = Cs[r][c] + bias[gcol];
      float p = Cs[r][c ^ 32] + bias[gcol ^ 32];
      int pos = pos_ids[grow];
      pos = pos < 0 ? 0 : (pos > 2047 ? 2047 : pos);
      int i = c & 31;
      float cs = rope[pos*64 + i];
      float sn = rope[pos*64 + 32 + i];
      x = ((c & 32) == 0) ? (x*cs - p*sn) : (x*cs + p*sn);
      o16[(size_t)grow*1024 + gcol] = (unsigned short)f2bfs(x);
    }
  } else {
    float* o32 = (float*)outv;
    #pragma unroll
    for (int jj = 0; jj < 32; jj++){
      int flat = t + jj*256;
      int r = flat >> 7, c = flat & 127;
      int grow = row0 + r, gcol = col0 + c;
      o32[(size_t)grow*1024 + gcol] = Cs[r][c] + bias[gcol];
    }
  }
}

// ---------- MFMA two-pass flash attention (r7 structure, bf16-staged inputs) ----------
// Block = (b, 16-row q-tile). 1024 threads = 16 waves; wave w = q-row owner w AND head owner w.
__global__ __launch_bounds__(1024) void attn_kernel(
    const unsigned short* __restrict__ qw, const unsigned short* __restrict__ kw,
    const unsigned short* __restrict__ vwT,
    const float* __restrict__ relk, const float* __restrict__ relv,
    const float* __restrict__ wpre_g, const float* __restrict__ wpost_g,
    float* __restrict__ ctx)
{
  __shared__ __align__(16) char pool[159632];
  short (*U_t)[40]      = (short(*)[40])(pool);               // [512=(i,j)][head] scores / exact attn
  short (*W_l)[16][48]  = (short(*)[16][48])(pool + 40960);   // qrel window, per-wave rows
  short (*Pp)[16][40]   = (short(*)[16][40])(pool + 65536);   // post-mixed attn [n][i][j]
  short (*Tt)[16][72]   = (short(*)[16][72])(pool + 86016);   // skewed post-mixed attn [n][i][p]
  short (*relv_s)[66]   = (short(*)[66])(pool + 122880);      // relv rows 128..256 bf16
  short (*relk_s)[68]   = (short(*)[68])(pool + 139912);      // relk rows 128..256 bf16
  float (*M_l)[17]      = (float(*)[17])(pool + 157456);      // [i][m] row max
  float (*il_l)[17]     = (float(*)[17])(pool + 158544);      // [i][m] 1/l

  int t = threadIdx.x;
  int h = t >> 6, lane = t & 63;
  int l15 = lane & 15, quad = lane >> 4;
  int b = blockIdx.x & 1;
  int q0 = (63 - (blockIdx.x >> 1)) << 4;   // descending q-tiles (longest first)

  { // zero U_t (cols>=16 stay 0) and Tt (unwritten skew slots stay 0)
    int* p0 = (int*)pool;
    for (int e = t; e < 10240; e += 1024) p0[e] = 0;
    int* p1 = (int*)(pool + 86016);
    for (int e = t; e < 9216; e += 1024) p1[e] = 0;
  }
  for (int e = t; e < 129*64; e += 1024){
    int r = e >> 6, d = e & 63;
    relv_s[r][d] = f2bfs(relv[(size_t)(128 + r)*64 + d]);
    relk_s[r][d] = f2bfs(relk[(size_t)(128 + r)*64 + d]);
  }

  // A-frags: awp = wpre^T, awq = wpost^T (contraction n padded 16->32 with zeros)
  v8s awp, awq;
  #pragma unroll
  for (int jj = 0; jj < 8; jj++){
    int n = quad*8 + jj;
    awp[jj] = (n < 16) ? f2bfs(wpre_g[n*16 + l15])  : (short)0;
    awq[jj] = (n < 16) ? f2bfs(wpost_g[n*16 + l15]) : (short)0;
  }
  // Q A-frags for head h (bf16, direct vector loads)
  v8s aq[2];
  {
    const unsigned short* qb = qw + ((size_t)(b*SEQ + q0 + l15))*1024 + h*64;
    #pragma unroll
    for (int c = 0; c < 2; c++) aq[c] = *(const v8s*)(qb + c*32 + quad*8);
  }
  __syncthreads();

  int nkt = (q0 + 47) >> 5;

  // ================= PASS 1: per (head m, q-row) running max & sum =================
  float M_st[4] = {-1e30f, -1e30f, -1e30f, -1e30f};
  float l_st[4] = {0.f, 0.f, 0.f, 0.f};

  for (int ci = 0; ci < nkt; ci++){
    int k0 = ci << 5;
    int r_lo = q0 - k0 - 31;

    v4f cqk[2];
    #pragma unroll
    for (int ct = 0; ct < 2; ct++){
      const unsigned short* kb = kw + ((size_t)(b*SEQ + k0 + ct*16 + l15))*1024 + h*64;
      v4f acc = (v4f){0.f,0.f,0.f,0.f};
      #pragma unroll
      for (int c = 0; c < 2; c++){
        v8s kv = *(const v8s*)(kb + c*32 + quad*8);
        acc = __builtin_amdgcn_mfma_f32_16x16x32_bf16(aq[c], kv, acc, 0, 0, 0);
      }
      cqk[ct] = acc;
    }
    #pragma unroll
    for (int pt = 0; pt < 3; pt++){
      int rr = r_lo + pt*16 + l15; rr = rr < 0 ? 0 : (rr > 128 ? 128 : rr);
      v4f acc = (v4f){0.f,0.f,0.f,0.f};
      #pragma unroll
      for (int c = 0; c < 2; c++){
        v8s rv = *(const v8s*)&relk_s[rr][c*32 + quad*8];
        acc = __builtin_amdgcn_mfma_f32_16x16x32_bf16(aq[c], rv, acc, 0, 0, 0);
      }
      #pragma unroll
      for (int reg = 0; reg < 4; reg++)
        W_l[h][quad*4 + reg][pt*16 + l15] = f2bfs(acc[reg]);
    }
    #pragma unroll
    for (int ct = 0; ct < 2; ct++)
      #pragma unroll
      for (int reg = 0; reg < 4; reg++){
        int i = quad*4 + reg, j = ct*16 + l15;
        float wv = bfl(W_l[h][i][i - j + 31]);
        U_t[i*32 + j][h] = f2bfs((cqk[ct][reg] + wv) * 0.125f);
      }
    __syncthreads();   // B1: U ready

    v4f cs[2];
    #pragma unroll
    for (int ct = 0; ct < 2; ct++){
      v8s bu = *(v8s*)&U_t[h*32 + ct*16 + l15][quad*8];
      cs[ct] = __builtin_amdgcn_mfma_f32_16x16x32_bf16(awp, bu, (v4f){0.f,0.f,0.f,0.f}, 0, 0, 0);
    }
    bool v0 = (k0 + l15)      <= (q0 + h);
    bool v1 = (k0 + 16 + l15) <= (q0 + h);
    #pragma unroll
    for (int reg = 0; reg < 4; reg++){
      float s0 = v0 ? cs[0][reg] : -1e4f;
      float s1 = v1 ? cs[1][reg] : -1e4f;
      float mx = fmaxf(s0, s1);
      mx = fmaxf(mx, __shfl_xor(mx, 1, 64));
      mx = fmaxf(mx, __shfl_xor(mx, 2, 64));
      mx = fmaxf(mx, __shfl_xor(mx, 4, 64));
      mx = fmaxf(mx, __shfl_xor(mx, 8, 64));
      float Mn = fmaxf(M_st[reg], mx);
      float al = __expf(fmaxf(M_st[reg] - Mn, -100.f));
      M_st[reg] = Mn;
      float p0 = v0 ? __expf(s0 - Mn) : 0.f;
      float p1 = v1 ? __expf(s1 - Mn) : 0.f;
      float sm = p0 + p1;
      sm += __shfl_xor(sm, 1, 64);
      sm += __shfl_xor(sm, 2, 64);
      sm += __shfl_xor(sm, 4, 64);
      sm += __shfl_xor(sm, 8, 64);
      l_st[reg] = l_st[reg]*al + sm;
    }
    __syncthreads();   // B2: U consumed
  }
  if (l15 == 0){
    #pragma unroll
    for (int reg = 0; reg < 4; reg++){
      M_l[quad*4 + reg][h]  = M_st[reg];
      il_l[quad*4 + reg][h] = 1.f / l_st[reg];
    }
  }
  __syncthreads();

  // ================= PASS 2: exact attn, post-mix, PV + rel_v =================
  float Mh[4], ilh[4];
  #pragma unroll
  for (int reg = 0; reg < 4; reg++){
    Mh[reg]  = M_l[quad*4 + reg][h];
    ilh[reg] = il_l[quad*4 + reg][h];
  }
  v4f o_acc[4];
  #pragma unroll
  for (int dt = 0; dt < 4; dt++) o_acc[dt] = (v4f){0.f,0.f,0.f,0.f};

  const unsigned short* vtb = vwT + ((size_t)(b*1024 + h*64))*1024;

  for (int ci = 0; ci < nkt; ci++){
    int k0 = ci << 5;
    int r_lo = q0 - k0 - 31;

    v4f cqk[2];
    #pragma unroll
    for (int ct = 0; ct < 2; ct++){
      const unsigned short* kb = kw + ((size_t)(b*SEQ + k0 + ct*16 + l15))*1024 + h*64;
      v4f acc = (v4f){0.f,0.f,0.f,0.f};
      #pragma unroll
      for (int c = 0; c < 2; c++){
        v8s kv = *(const v8s*)(kb + c*32 + quad*8);
        acc = __builtin_amdgcn_mfma_f32_16x16x32_bf16(aq[c], kv, acc, 0, 0, 0);
      }
      cqk[ct] = acc;
    }
    #pragma unroll
    for (int pt = 0; pt < 3; pt++){
      int rr = r_lo + pt*16 + l15; rr = rr < 0 ? 0 : (rr > 128 ? 128 : rr);
      v4f acc = (v4f){0.f,0.f,0.f,0.f};
      #pragma unroll
      for (int c = 0; c < 2; c++){
        v8s rv = *(const v8s*)&relk_s[rr][c*32 + quad*8];
        acc = __builtin_amdgcn_mfma_f32_16x16x32_bf16(aq[c], rv, acc, 0, 0, 0);
      }
      #pragma unroll
      for (int reg = 0; reg < 4; reg++)
        W_l[h][quad*4 + reg][pt*16 + l15] = f2bfs(acc[reg]);
    }
    #pragma unroll
    for (int ct = 0; ct < 2; ct++)
      #pragma unroll
      for (int reg = 0; reg < 4; reg++){
        int i = quad*4 + reg, j = ct*16 + l15;
        float wv = bfl(W_l[h][i][i - j + 31]);
        U_t[i*32 + j][h] = f2bfs((cqk[ct][reg] + wv) * 0.125f);
      }
    __syncthreads();   // B1

    v4f cs[2];
    #pragma unroll
    for (int ct = 0; ct < 2; ct++){
      v8s bu = *(v8s*)&U_t[h*32 + ct*16 + l15][quad*8];
      cs[ct] = __builtin_amdgcn_mfma_f32_16x16x32_bf16(awp, bu, (v4f){0.f,0.f,0.f,0.f}, 0, 0, 0);
    }
    bool v0 = (k0 + l15)      <= (q0 + h);
    bool v1 = (k0 + 16 + l15) <= (q0 + h);
    float pr[2][4];
    #pragma unroll
    for (int reg = 0; reg < 4; reg++){
      pr[0][reg] = v0 ? __expf(cs[0][reg] - Mh[reg]) * ilh[reg] : 0.f;
      pr[1][reg] = v1 ? __expf(cs[1][reg] - Mh[reg]) * ilh[reg] : 0.f;
    }
    __syncthreads();   // B2: overwrite U_t with exact attn (At[(i,j)][m])

    #pragma unroll
    for (int ct = 0; ct < 2; ct++)
      #pragma unroll
      for (int reg = 0; reg < 4; reg++)
        U_t[h*32 + ct*16 + l15][quad*4 + reg] = f2bfs(pr[ct][reg]);
    __syncthreads();   // B3: At ready

    // post-mix: attn_post[n][i=h][j]
    #pragma unroll
    for (int ct = 0; ct < 2; ct++){
      v8s bu = *(v8s*)&U_t[h*32 + ct*16 + l15][quad*8];
      v4f cp = __builtin_amdgcn_mfma_f32_16x16x32_bf16(awq, bu, (v4f){0.f,0.f,0.f,0.f}, 0, 0, 0);
      #pragma unroll
      for (int reg = 0; reg < 4; reg++){
        int n = quad*4 + reg, j = ct*16 + l15;
        short pb = f2bfs(cp[reg]);
        Pp[n][h][j] = pb;
        Tt[n][h][h + 31 - j] = pb;
      }
    }
    __syncthreads();   // B4: Pp/Tt ready

    // PV with head h's V (transposed bf16 -> contiguous B-frags) + skewed rel_v
    v8s ap = *(v8s*)&Pp[h][l15][quad*8];
    #pragma unroll
    for (int dt = 0; dt < 4; dt++){
      v8s bv = *(const v8s*)(vtb + (size_t)(dt*16 + l15)*1024 + k0 + quad*8);
      o_acc[dt] = __builtin_amdgcn_mfma_f32_16x16x32_bf16(ap, bv, o_acc[dt], 0, 0, 0);
    }
    #pragma unroll
    for (int ch = 0; ch < 2; ch++){
      v8s at = *(v8s*)&Tt[h][l15][ch*32 + quad*8];
      #pragma unroll
      for (int dt = 0; dt < 4; dt++){
        v8s br;
        #pragma unroll
        for (int jj = 0; jj < 8; jj++){
          int rr = r_lo + ch*32 + quad*8 + jj;
          rr = rr < 0 ? 0 : (rr > 128 ? 128 : rr);
          br[jj] = relv_s[rr][dt*16 + l15];
        }
        o_acc[dt] = __builtin_amdgcn_mfma_f32_16x16x32_bf16(at, br, o_acc[dt], 0, 0, 0);
      }
    }
  }

  // ---- epilogue: o_acc final (normalized, post-mixed); write head h (fp32) ----
  #pragma unroll
  for (int dt = 0; dt < 4; dt++)
    #pragma unroll
    for (int reg = 0; reg < 4; reg++)
      ctx[((size_t)(b*SEQ + q0 + quad*4 + reg))*1024 + h*64 + dt*16 + l15] = o_acc[dt][reg];
}

extern "C" void kernel_launch(void* const* d_in, const int* in_sizes, int n_in,
                              void* d_out, int out_size, void* d_ws, size_t ws_size,
                              hipStream_t stream)
{
  int ip = -1;
  for (int i = 0; i < n_in; i++){
    if (in_sizes[i] == 2048){ ip = i; break; }
  }
  if (ip < 0) ip = 4;

  const float* query = (const float*)d_in[0];
  const float* key   = (const float*)d_in[1];
  const float* value = (const float*)d_in[2];
  const int* qpos = (const int*)d_in[ip];
  const int* kpos = (const int*)d_in[ip + 1];
  const float* Wq    = (const float*)d_in[ip + 2];
  const float* bq    = (const float*)d_in[ip + 3];
  const float* Wk    = (const float*)d_in[ip + 4];
  const float* bk    = (const float*)d_in[ip + 5];
  const float* Wv    = (const float*)d_in[ip + 6];
  const float* b_v   = (const float*)d_in[ip + 7];
  const float* Wo    = (const float*)d_in[ip + 8];
  const float* bo    = (const float*)d_in[ip + 9];
  const float* relk  = (const float*)d_in[ip + 10];
  const float* relv  = (const float*)d_in[ip + 11];
  const float* wpre  = (const float*)d_in[ip + 12];
  const float* wpost = (const float*)d_in[ip + 13];

  char* ws = (char*)d_ws;
  float* rope            = (float*)ws;                          // 512 KB
  unsigned short* q_ws   = (unsigned short*)(ws + 524288);      // 4 MB bf16
  unsigned short* k_ws   = (unsigned short*)(ws + 524288 + 4194304);
  unsigned short* v_ws   = (unsigned short*)(ws + 524288 + 2*4194304);  // transposed bf16
  float* ctx             = (float*)(ws + 524288 + 3*4194304);   // 8 MB fp32

  hipLaunchKernelGGL(rope_table_kernel, dim3(256), dim3(256), 0, stream, rope);
  dim3 gg(8, 32);
  hipLaunchKernelGGL(gemm_kernel, gg, dim3(256), 0, stream, query, Wq, bq, (void*)q_ws, rope, qpos, 1);
  hipLaunchKernelGGL(gemm_kernel, gg, dim3(256), 0, stream, key,   Wk, bk, (void*)k_ws, rope, kpos, 1);
  hipLaunchKernelGGL(gemm_kernel, gg, dim3(256), 0, stream, value, Wv, b_v, (void*)v_ws, rope, qpos, 2);
  hipLaunchKernelGGL(attn_kernel, dim3(128), dim3(1024), 0, stream,
                     q_ws, k_ws, v_ws, relk, relv, wpre, wpost, ctx);
  hipLaunchKernelGGL(gemm_kernel, gg, dim3(256), 0, stream, ctx, Wo, bo,
                     (void*)d_out, rope, qpos, 0);
}

// Round 9
// 388.971 us; speedup vs baseline: 6.3814x; 1.6851x over previous
//
#include <hip/hip_runtime.h>

#define SEQ 1024

typedef short v8s __attribute__((ext_vector_type(8)));
typedef short v4s_t __attribute__((ext_vector_type(4)));
typedef float v4f __attribute__((ext_vector_type(4)));

__device__ __forceinline__ short f2bfs(float f){
  unsigned int u = __float_as_uint(f);
  u += 0x7fffu + ((u >> 16) & 1u);
  return (short)(u >> 16);
}
__device__ __forceinline__ float bfl(short s){
  return __uint_as_float(((unsigned int)(unsigned short)s) << 16);
}

// ---------------- RoPE cos/sin table ----------------
__global__ void rope_table_kernel(float* __restrict__ rope){
  int idx = blockIdx.x * 256 + threadIdx.x;
  if (idx >= 2048 * 32) return;
  int pos = idx >> 5, i = idx & 31;
  double freq = pow(10000.0, -(double)i / 32.0);
  double a = (double)pos * freq;
  rope[pos * 64 + i]      = (float)cos(a);
  rope[pos * 64 + 32 + i] = (float)sin(a);
}

// ---- MFMA GEMM: C[2048,1024] = A @ W^T + bias.
// mode 0: fp32 out. mode 1: bf16 out + RoPE. mode 2: bf16 transposed out.
// mode 3: fp32 out, A-staging sums A + A2 (for split-attention partial ctx).
__global__ __launch_bounds__(256) void gemm_kernel(
    const float* __restrict__ A, const float* __restrict__ A2,
    const float* __restrict__ W,
    const float* __restrict__ bias, void* __restrict__ outv,
    const float* __restrict__ rope, const int* __restrict__ pos_ids, int mode)
{
  __shared__ short As[64][40];
  __shared__ short Ws[128][40];
  __shared__ float Cs[64][133];

  int t = threadIdx.x;
  int lane = t & 63, wave = t >> 6;
  int l15 = lane & 15, quad = lane >> 4;
  int wm = wave >> 1, wn = wave & 1;
  int row0 = blockIdx.y << 6;
  int col0 = blockIdx.x << 7;

  v4f acc[2][4];
  #pragma unroll
  for (int i = 0; i < 2; i++)
    #pragma unroll
    for (int j = 0; j < 4; j++)
      acc[i][j] = (v4f){0.f, 0.f, 0.f, 0.f};

  int ar = t >> 2, ac = (t & 3) * 8;
  int wr = t >> 1, wc = (t & 1) * 16;
  const float* apb  = A  + (size_t)(row0 + ar)*1024 + ac;
  const float* apb2 = A2 + (size_t)(row0 + ar)*1024 + ac;
  const float* wpb  = W  + (size_t)(col0 + wr)*1024 + wc;

  for (int kt = 0; kt < 1024; kt += 32){
    float4 a0 = *(const float4*)(apb + kt), a1 = *(const float4*)(apb + kt + 4);
    if (mode == 3){
      float4 b0 = *(const float4*)(apb2 + kt), b1 = *(const float4*)(apb2 + kt + 4);
      a0.x += b0.x; a0.y += b0.y; a0.z += b0.z; a0.w += b0.w;
      a1.x += b1.x; a1.y += b1.y; a1.z += b1.z; a1.w += b1.w;
    }
    v8s av = { f2bfs(a0.x), f2bfs(a0.y), f2bfs(a0.z), f2bfs(a0.w),
               f2bfs(a1.x), f2bfs(a1.y), f2bfs(a1.z), f2bfs(a1.w) };
    *(v8s*)&As[ar][ac] = av;

    const float* wp = wpb + kt;
    float4 w0 = *(const float4*)wp,     w1 = *(const float4*)(wp + 4);
    float4 w2 = *(const float4*)(wp+8), w3 = *(const float4*)(wp + 12);
    v8s wv0 = { f2bfs(w0.x), f2bfs(w0.y), f2bfs(w0.z), f2bfs(w0.w),
                f2bfs(w1.x), f2bfs(w1.y), f2bfs(w1.z), f2bfs(w1.w) };
    v8s wv1 = { f2bfs(w2.x), f2bfs(w2.y), f2bfs(w2.z), f2bfs(w2.w),
                f2bfs(w3.x), f2bfs(w3.y), f2bfs(w3.z), f2bfs(w3.w) };
    *(v8s*)&Ws[wr][wc]     = wv0;
    *(v8s*)&Ws[wr][wc + 8] = wv1;
    __syncthreads();

    v8s af[2], bfq[4];
    #pragma unroll
    for (int i = 0; i < 2; i++) af[i]  = *(v8s*)&As[wm*32 + i*16 + l15][quad*8];
    #pragma unroll
    for (int j = 0; j < 4; j++) bfq[j] = *(v8s*)&Ws[wn*64 + j*16 + l15][quad*8];
    #pragma unroll
    for (int i = 0; i < 2; i++)
      #pragma unroll
      for (int j = 0; j < 4; j++)
        acc[i][j] = __builtin_amdgcn_mfma_f32_16x16x32_bf16(af[i], bfq[j], acc[i][j], 0, 0, 0);
    __syncthreads();
  }

  #pragma unroll
  for (int i = 0; i < 2; i++)
    #pragma unroll
    for (int j = 0; j < 4; j++)
      #pragma unroll
      for (int r = 0; r < 4; r++)
        Cs[wm*32 + i*16 + quad*4 + r][wn*64 + j*16 + l15] = acc[i][j][r];
  __syncthreads();

  if (mode == 2){
    unsigned short* o16 = (unsigned short*)outv;
    #pragma unroll
    for (int jj = 0; jj < 32; jj++){
      int flat = t + jj*256;
      int sl = flat & 63, c = flat >> 6;
      int grow = row0 + sl, gcol = col0 + c;
      float x = Cs[sl][c] + bias[gcol];
      int bb = grow >> 10, s = grow & 1023;
      o16[((size_t)(bb*1024 + gcol))*1024 + s] = (unsigned short)f2bfs(x);
    }
  } else if (mode == 1){
    unsigned short* o16 = (unsigned short*)outv;
    #pragma unroll
    for (int jj = 0; jj < 32; jj++){
      int flat = t + jj*256;
      int r = flat >> 7, c = flat & 127;
      int grow = row0 + r, gcol = col0 + c;
      float x = Cs[r][c] + bias[gcol];
      float p = Cs[r][c ^ 32] + bias[gcol ^ 32];
      int pos = pos_ids[grow];
      pos = pos < 0 ? 0 : (pos > 2047 ? 2047 : pos);
      int i = c & 31;
      float cs = rope[pos*64 + i];
      float sn = rope[pos*64 + 32 + i];
      x = ((c & 32) == 0) ? (x*cs - p*sn) : (x*cs + p*sn);
      o16[(size_t)grow*1024 + gcol] = (unsigned short)f2bfs(x);
    }
  } else {
    float* o32 = (float*)outv;
    #pragma unroll
    for (int jj = 0; jj < 32; jj++){
      int flat = t + jj*256;
      int r = flat >> 7, c = flat & 127;
      int grow = row0 + r, gcol = col0 + c;
      o32[(size_t)grow*1024 + gcol] = Cs[r][c] + bias[gcol];
    }
  }
}

// ---------- attention pass 1: scores + (M,l) partials; 256 blocks = (b,qt,k-half) ----------
__global__ __launch_bounds__(1024) void attn_pass1(
    const unsigned short* __restrict__ qw, const unsigned short* __restrict__ kw,
    const float* __restrict__ relk, const float* __restrict__ wpre_g,
    unsigned short* __restrict__ Sp, float* __restrict__ Mp, float* __restrict__ Lp)
{
  __shared__ short U_t[512][40];      // raw mixed scores, [(i*32+j)][head], cols>=16 zero
  __shared__ short W_l[16][16][48];   // near-tile qrel window (wave-private rows)
  __shared__ short relk_s[129][68];   // relk rows 128..256 bf16

  int t = threadIdx.x;
  int h = t >> 6, lane = t & 63;
  int l15 = lane & 15, quad = lane >> 4;
  int bid = blockIdx.x;
  int half = bid & 1;
  int b = (bid >> 1) & 1;
  int qt = 63 - (bid >> 2);
  int q0 = qt << 4;
  int nkt = (qt + 2) >> 1;
  int hq = qt >> 1;
  int offt = hq*(hq+1) + ((qt & 1) ? (hq + 1) : 0);
  unsigned short* Sbase = Sp + ((size_t)(b*1056 + offt)) * 8192;

  { int* p0 = (int*)U_t; for (int e = t; e < 10240; e += 1024) p0[e] = 0; }
  for (int e = t; e < 129*64; e += 1024)
    relk_s[e >> 6][e & 63] = f2bfs(relk[(size_t)(128 + (e >> 6))*64 + (e & 63)]);

  v8s awp;
  #pragma unroll
  for (int jj = 0; jj < 8; jj++){
    int n = quad*8 + jj;
    awp[jj] = (n < 16) ? f2bfs(wpre_g[n*16 + l15]) : (short)0;
  }
  v8s aq[2];
  {
    const unsigned short* qb = qw + ((size_t)(b*SEQ + q0 + l15))*1024 + h*64;
    #pragma unroll
    for (int c = 0; c < 2; c++) aq[c] = *(const v8s*)(qb + c*32 + quad*8);
  }
  __syncthreads();

  // far-tile constant: qrel_inf[i] = Q[i] . relk[256]  (one MFMA pair, broadcast B)
  v4f cinf = (v4f){0.f,0.f,0.f,0.f};
  #pragma unroll
  for (int c = 0; c < 2; c++){
    v8s binf = *(v8s*)&relk_s[128][c*32 + quad*8];
    cinf = __builtin_amdgcn_mfma_f32_16x16x32_bf16(aq[c], binf, cinf, 0, 0, 0);
  }

  float M_st[4] = {-1e30f, -1e30f, -1e30f, -1e30f};
  float l_st[4] = {0.f, 0.f, 0.f, 0.f};

  // prefetch K frags for first tile
  v8s kc[2][2];
  {
    int k0 = half << 5;
    if (half < nkt){
      #pragma unroll
      for (int ct = 0; ct < 2; ct++){
        const unsigned short* kb = kw + ((size_t)(b*SEQ + k0 + ct*16 + l15))*1024 + h*64;
        #pragma unroll
        for (int c = 0; c < 2; c++) kc[ct][c] = *(const v8s*)(kb + c*32 + quad*8);
      }
    }
  }

  for (int ci = half; ci < nkt; ci += 2){
    int k0 = ci << 5;
    int r_lo = q0 - k0 - 31;
    bool far = (r_lo >= 128);

    v4f cqk[2];
    #pragma unroll
    for (int ct = 0; ct < 2; ct++){
      v4f acc = (v4f){0.f,0.f,0.f,0.f};
      #pragma unroll
      for (int c = 0; c < 2; c++)
        acc = __builtin_amdgcn_mfma_f32_16x16x32_bf16(aq[c], kc[ct][c], acc, 0, 0, 0);
      cqk[ct] = acc;
    }
    // prefetch next tile's K
    v8s kn[2][2];
    {
      int cin = ci + 2;
      int k0n = ((cin < nkt) ? cin : ci) << 5;
      #pragma unroll
      for (int ct = 0; ct < 2; ct++){
        const unsigned short* kb = kw + ((size_t)(b*SEQ + k0n + ct*16 + l15))*1024 + h*64;
        #pragma unroll
        for (int c = 0; c < 2; c++) kn[ct][c] = *(const v8s*)(kb + c*32 + quad*8);
      }
    }

    if (!far){
      #pragma unroll
      for (int pt = 0; pt < 3; pt++){
        int rr = r_lo + pt*16 + l15; rr = rr < 0 ? 0 : (rr > 128 ? 128 : rr);
        v4f acc = (v4f){0.f,0.f,0.f,0.f};
        #pragma unroll
        for (int c = 0; c < 2; c++){
          v8s rv = *(v8s*)&relk_s[rr][c*32 + quad*8];
          acc = __builtin_amdgcn_mfma_f32_16x16x32_bf16(aq[c], rv, acc, 0, 0, 0);
        }
        #pragma unroll
        for (int reg = 0; reg < 4; reg++)
          W_l[h][quad*4 + reg][pt*16 + l15] = f2bfs(acc[reg]);
      }
    }
    #pragma unroll
    for (int ct = 0; ct < 2; ct++)
      #pragma unroll
      for (int reg = 0; reg < 4; reg++){
        int i = quad*4 + reg, j = ct*16 + l15;
        float wv = far ? cinf[reg] : bfl(W_l[h][i][i - j + 31]);
        U_t[i*32 + j][h] = f2bfs((cqk[ct][reg] + wv) * 0.125f);
      }
    __syncthreads();   // B1: U ready

    v4f cs[2];
    #pragma unroll
    for (int ct = 0; ct < 2; ct++){
      v8s bu = *(v8s*)&U_t[h*32 + ct*16 + l15][quad*8];
      cs[ct] = __builtin_amdgcn_mfma_f32_16x16x32_bf16(awp, bu, (v4f){0.f,0.f,0.f,0.f}, 0, 0, 0);
    }
    // round to bf16, store S' (coalesced), use ROUNDED values for (M,l)
    short sb[2][4];
    unsigned short* stile = Sbase + (size_t)ci * 8192;
    #pragma unroll
    for (int ct = 0; ct < 2; ct++){
      #pragma unroll
      for (int reg = 0; reg < 4; reg++) sb[ct][reg] = f2bfs(cs[ct][reg]);
      uint2 pk;
      pk.x = ((unsigned int)(unsigned short)sb[ct][0]) | (((unsigned int)(unsigned short)sb[ct][1]) << 16);
      pk.y = ((unsigned int)(unsigned short)sb[ct][2]) | (((unsigned int)(unsigned short)sb[ct][3]) << 16);
      *(uint2*)(stile + ((size_t)((h*2 + ct)*64 + quad*16 + l15))*4) = pk;
    }
    bool v0 = (k0 + l15)      <= (q0 + h);
    bool v1 = (k0 + 16 + l15) <= (q0 + h);
    #pragma unroll
    for (int reg = 0; reg < 4; reg++){
      float s0 = v0 ? bfl(sb[0][reg]) : -1e4f;
      float s1 = v1 ? bfl(sb[1][reg]) : -1e4f;
      float mx = fmaxf(s0, s1);
      mx = fmaxf(mx, __shfl_xor(mx, 1, 64));
      mx = fmaxf(mx, __shfl_xor(mx, 2, 64));
      mx = fmaxf(mx, __shfl_xor(mx, 4, 64));
      mx = fmaxf(mx, __shfl_xor(mx, 8, 64));
      float Mn = fmaxf(M_st[reg], mx);
      float al = __expf(fmaxf(M_st[reg] - Mn, -100.f));
      M_st[reg] = Mn;
      float p0 = v0 ? __expf(s0 - Mn) : 0.f;
      float p1 = v1 ? __expf(s1 - Mn) : 0.f;
      float sm = p0 + p1;
      sm += __shfl_xor(sm, 1, 64);
      sm += __shfl_xor(sm, 2, 64);
      sm += __shfl_xor(sm, 4, 64);
      sm += __shfl_xor(sm, 8, 64);
      l_st[reg] = l_st[reg]*al + sm;
    }
    __syncthreads();   // B2: U reusable
    #pragma unroll
    for (int ct = 0; ct < 2; ct++)
      #pragma unroll
      for (int c = 0; c < 2; c++) kc[ct][c] = kn[ct][c];
  }

  // write (M,l) partials: [b][qt][half][i=h][n]
  size_t pb = ((((size_t)b*64 + qt)*2 + half)*16 + h)*16;
  if (l15 == 0){
    #pragma unroll
    for (int reg = 0; reg < 4; reg++){
      Mp[pb + quad*4 + reg] = M_st[reg];
      Lp[pb + quad*4 + reg] = l_st[reg];
    }
  }
}

// ---------- attention pass 2: exact attn from stored S', post-mix, PV + rel_v ----------
__global__ __launch_bounds__(1024) void attn_pass2(
    const unsigned short* __restrict__ Sp, const unsigned short* __restrict__ vwT,
    const float* __restrict__ relv, const float* __restrict__ wpost_g,
    const float* __restrict__ Mp, const float* __restrict__ Lp,
    float* __restrict__ ctxA, float* __restrict__ ctxB)
{
  __shared__ short U_t[512][40];      // exact attn, [(i*32+j)][head]
  __shared__ short Pp[16][16][40];    // post-mixed attn [n][i][j]
  __shared__ short Tt[16][16][72];    // skewed post-mixed attn [n][i][p] (near tiles)
  __shared__ short relv_s[129][66];
  __shared__ float M_f[16][17], il_f[16][17], Srow[16][17];

  int t = threadIdx.x;
  int h = t >> 6, lane = t & 63;
  int l15 = lane & 15, quad = lane >> 4;
  int bid = blockIdx.x;
  int half = bid & 1;
  int b = (bid >> 1) & 1;
  int qt = 63 - (bid >> 2);
  int q0 = qt << 4;
  int nkt = (qt + 2) >> 1;
  int hq = qt >> 1;
  int offt = hq*(hq+1) + ((qt & 1) ? (hq + 1) : 0);
  const unsigned short* Sbase = Sp + ((size_t)(b*1056 + offt)) * 8192;
  float* ctx = (half == 0) ? ctxA : ctxB;

  { int* p0 = (int*)U_t; for (int e = t; e < 10240; e += 1024) p0[e] = 0; }
  { int* p1 = (int*)Tt;  for (int e = t; e < 9216;  e += 1024) p1[e] = 0; }
  for (int e = t; e < 129*64; e += 1024)
    relv_s[e >> 6][e & 63] = f2bfs(relv[(size_t)(128 + (e >> 6))*64 + (e & 63)]);
  if (t < 256){
    int i = t >> 4, n = t & 15;
    Srow[i][n] = 0.f;
    size_t b0 = (((size_t)b*64 + qt)*2 + 0)*256 + (size_t)i*16 + n;
    float M0 = Mp[b0], M1 = Mp[b0 + 256];
    float L0 = Lp[b0], L1 = Lp[b0 + 256];
    float M = fmaxf(M0, M1);
    float l = L0*__expf(M0 - M) + L1*__expf(M1 - M);
    M_f[i][n]  = M;
    il_f[i][n] = 1.f / l;
  }
  v8s awq;
  #pragma unroll
  for (int jj = 0; jj < 8; jj++){
    int n = quad*8 + jj;
    awq[jj] = (n < 16) ? f2bfs(wpost_g[n*16 + l15]) : (short)0;
  }
  __syncthreads();

  v4f o_acc[4];
  #pragma unroll
  for (int dt = 0; dt < 4; dt++) o_acc[dt] = (v4f){0.f,0.f,0.f,0.f};

  const unsigned short* vtb = vwT + ((size_t)(b*1024 + h*64))*1024;

  uint4 sv;
  if (half < nkt) sv = *(const uint4*)(Sbase + (size_t)half*8192 + (size_t)t*8);

  for (int ci = half; ci < nkt; ci += 2){
    int k0 = ci << 5;
    int r_lo = q0 - k0 - 31;
    bool far = (r_lo >= 128);

    // stage exact attn from stored S'
    #pragma unroll
    for (int g = 0; g < 2; g++){
      unsigned int w0 = (g == 0) ? sv.x : sv.z;
      unsigned int w1 = (g == 0) ? sv.y : sv.w;
      int v = t*2 + g;
      int i = v >> 7, ct = (v >> 6) & 1, quadv = (v >> 4) & 3, lv = v & 15;
      int j = ct*16 + lv;
      bool valid = (k0 + j) <= (q0 + i);
      v4s_t at;
      unsigned short ss[4] = { (unsigned short)(w0 & 0xffff), (unsigned short)(w0 >> 16),
                               (unsigned short)(w1 & 0xffff), (unsigned short)(w1 >> 16) };
      #pragma unroll
      for (int reg = 0; reg < 4; reg++){
        int n = quadv*4 + reg;
        float a = valid ? __expf(bfl((short)ss[reg]) - M_f[i][n]) * il_f[i][n] : 0.f;
        at[reg] = f2bfs(a);
      }
      *(v4s_t*)&U_t[i*32 + j][quadv*4] = at;
    }
    __syncthreads();   // B1: At ready

    // post-mix
    v4f cp[2];
    #pragma unroll
    for (int ct = 0; ct < 2; ct++){
      v8s bu = *(v8s*)&U_t[h*32 + ct*16 + l15][quad*8];
      cp[ct] = __builtin_amdgcn_mfma_f32_16x16x32_bf16(awq, bu, (v4f){0.f,0.f,0.f,0.f}, 0, 0, 0);
    }
    #pragma unroll
    for (int ct = 0; ct < 2; ct++)
      #pragma unroll
      for (int reg = 0; reg < 4; reg++){
        int n = quad*4 + reg, j = ct*16 + l15;
        short pb = f2bfs(cp[ct][reg]);
        Pp[n][h][j] = pb;
        if (!far) Tt[n][h][h + 31 - j] = pb;
      }
    if (far){
      #pragma unroll
      for (int reg = 0; reg < 4; reg++){
        float s = cp[0][reg] + cp[1][reg];
        s += __shfl_xor(s, 1, 64);
        s += __shfl_xor(s, 2, 64);
        s += __shfl_xor(s, 4, 64);
        s += __shfl_xor(s, 8, 64);
        if (l15 == 0) Srow[quad*4 + reg][h] += s;
      }
    }
    __syncthreads();   // B2: Pp/Tt/Srow ready

    // prefetch next tile's S'
    {
      int cin = ci + 2;
      int cld = (cin < nkt) ? cin : ci;
      sv = *(const uint4*)(Sbase + (size_t)cld*8192 + (size_t)t*8);
    }

    // PV (head h) + near-tile skewed rel_v
    v8s ap = *(v8s*)&Pp[h][l15][quad*8];
    #pragma unroll
    for (int dt = 0; dt < 4; dt++){
      v8s bv = *(const v8s*)(vtb + (size_t)(dt*16 + l15)*1024 + k0 + quad*8);
      o_acc[dt] = __builtin_amdgcn_mfma_f32_16x16x32_bf16(ap, bv, o_acc[dt], 0, 0, 0);
    }
    if (!far){
      #pragma unroll
      for (int ch = 0; ch < 2; ch++){
        v8s at2 = *(v8s*)&Tt[h][l15][ch*32 + quad*8];
        #pragma unroll
        for (int dt = 0; dt < 4; dt++){
          v8s br;
          #pragma unroll
          for (int jj = 0; jj < 8; jj++){
            int rr = r_lo + ch*32 + quad*8 + jj;
            rr = rr < 0 ? 0 : (rr > 128 ? 128 : rr);
            br[jj] = relv_s[rr][dt*16 + l15];
          }
          o_acc[dt] = __builtin_amdgcn_mfma_f32_16x16x32_bf16(at2, br, o_acc[dt], 0, 0, 0);
        }
      }
    }
  }
  __syncthreads();   // Srow final

  // far-tile rel_v contribution + write partial ctx (half buffer)
  #pragma unroll
  for (int dt = 0; dt < 4; dt++)
    #pragma unroll
    for (int reg = 0; reg < 4; reg++){
      float o = o_acc[dt][reg] + Srow[h][quad*4 + reg] * bfl(relv_s[128][dt*16 + l15]);
      ctx[((size_t)(b*SEQ + q0 + quad*4 + reg))*1024 + h*64 + dt*16 + l15] = o;
    }
}

extern "C" void kernel_launch(void* const* d_in, const int* in_sizes, int n_in,
                              void* d_out, int out_size, void* d_ws, size_t ws_size,
                              hipStream_t stream)
{
  int ip = -1;
  for (int i = 0; i < n_in; i++){
    if (in_sizes[i] == 2048){ ip = i; break; }
  }
  if (ip < 0) ip = 4;

  const float* query = (const float*)d_in[0];
  const float* key   = (const float*)d_in[1];
  const float* value = (const float*)d_in[2];
  const int* qpos = (const int*)d_in[ip];
  const int* kpos = (const int*)d_in[ip + 1];
  const float* Wq    = (const float*)d_in[ip + 2];
  const float* bq    = (const float*)d_in[ip + 3];
  const float* Wk    = (const float*)d_in[ip + 4];
  const float* bk    = (const float*)d_in[ip + 5];
  const float* Wv    = (const float*)d_in[ip + 6];
  const float* b_v   = (const float*)d_in[ip + 7];
  const float* Wo    = (const float*)d_in[ip + 8];
  const float* bo    = (const float*)d_in[ip + 9];
  const float* relk  = (const float*)d_in[ip + 10];
  const float* relv  = (const float*)d_in[ip + 11];
  const float* wpre  = (const float*)d_in[ip + 12];
  const float* wpost = (const float*)d_in[ip + 13];

  char* ws = (char*)d_ws;
  float* rope           = (float*)ws;                                   // 512 KB
  unsigned short* q_ws  = (unsigned short*)(ws + 524288);               // 4 MB bf16
  unsigned short* k_ws  = (unsigned short*)(ws + 524288 + 4194304);     // 4 MB
  unsigned short* v_ws  = (unsigned short*)(ws + 524288 + 2*4194304);   // 4 MB transposed
  float* ctxA           = (float*)(ws + 524288 + 3*4194304);            // 8 MB
  float* ctxB           = (float*)(ws + 524288 + 3*4194304 + 8388608);  // 8 MB
  unsigned short* Sp    = (unsigned short*)(ws + 524288 + 3*4194304 + 2*8388608);  // 34.6 MB
  float* Mp             = (float*)(ws + 64487424);                      // 256 KB
  float* Lp             = (float*)(ws + 64487424 + 262144);             // 256 KB

  hipLaunchKernelGGL(rope_table_kernel, dim3(256), dim3(256), 0, stream, rope);
  dim3 gg(8, 32);
  hipLaunchKernelGGL(gemm_kernel, gg, dim3(256), 0, stream, query, query, Wq, bq, (void*)q_ws, rope, qpos, 1);
  hipLaunchKernelGGL(gemm_kernel, gg, dim3(256), 0, stream, key,   key,   Wk, bk, (void*)k_ws, rope, kpos, 1);
  hipLaunchKernelGGL(gemm_kernel, gg, dim3(256), 0, stream, value, value, Wv, b_v, (void*)v_ws, rope, qpos, 2);
  hipLaunchKernelGGL(attn_pass1, dim3(256), dim3(1024), 0, stream,
                     q_ws, k_ws, relk, wpre, Sp, Mp, Lp);
  hipLaunchKernelGGL(attn_pass2, dim3(256), dim3(1024), 0, stream,
                     Sp, v_ws, relv, wpost, Mp, Lp, ctxA, ctxB);
  hipLaunchKernelGGL(gemm_kernel, gg, dim3(256), 0, stream, ctxA, ctxB, Wo, bo,
                     (void*)d_out, rope, qpos, 3);
}

// Round 10
// 316.157 us; speedup vs baseline: 7.8511x; 1.2303x over previous
//
#include <hip/hip_runtime.h>

#define SEQ 1024

typedef short v8s __attribute__((ext_vector_type(8)));
typedef short v4s_t __attribute__((ext_vector_type(4)));
typedef float v4f __attribute__((ext_vector_type(4)));

__device__ __forceinline__ short f2bfs(float f){
  unsigned int u = __float_as_uint(f);
  u += 0x7fffu + ((u >> 16) & 1u);
  return (short)(u >> 16);
}
__device__ __forceinline__ float bfl(short s){
  return __uint_as_float(((unsigned int)(unsigned short)s) << 16);
}

// ---------------- RoPE cos/sin table ----------------
__global__ void rope_table_kernel(float* __restrict__ rope){
  int idx = blockIdx.x * 256 + threadIdx.x;
  if (idx >= 2048 * 32) return;
  int pos = idx >> 5, i = idx & 31;
  double freq = exp2(-13.287712379549449 * (double)i / 32.0);  // 10000^(-i/32)
  double a = (double)pos * freq;
  rope[pos * 64 + i]      = (float)cos(a);
  rope[pos * 64 + 32 + i] = (float)sin(a);
}

// ---------------- fp32 -> bf16 bulk convert (q,k,v,Wq,Wk,Wv,Wo) ----------------
__global__ __launch_bounds__(256) void conv_kernel(
    const float* __restrict__ q, const float* __restrict__ k, const float* __restrict__ v,
    const float* __restrict__ wq, const float* __restrict__ wk2, const float* __restrict__ wv2,
    const float* __restrict__ wo, unsigned short* __restrict__ dst)
{
  size_t e0 = ((size_t)blockIdx.x * 256 + threadIdx.x) * 8;   // 10,485,760 elems total
  const float* src; size_t off;
  if      (e0 <  2097152){ src = q;   off = e0; }
  else if (e0 <  4194304){ src = k;   off = e0 - 2097152; }
  else if (e0 <  6291456){ src = v;   off = e0 - 4194304; }
  else if (e0 <  7340032){ src = wq;  off = e0 - 6291456; }
  else if (e0 <  8388608){ src = wk2; off = e0 - 7340032; }
  else if (e0 <  9437184){ src = wv2; off = e0 - 8388608; }
  else                   { src = wo;  off = e0 - 9437184; }
  float4 a = *(const float4*)(src + off);
  float4 b = *(const float4*)(src + off + 4);
  v8s o = { f2bfs(a.x), f2bfs(a.y), f2bfs(a.z), f2bfs(a.w),
            f2bfs(b.x), f2bfs(b.y), f2bfs(b.z), f2bfs(b.w) };
  *(v8s*)(dst + e0) = o;
}

// ---- MFMA GEMM: C[2048,1024] = A @ W^T + bias. A and W are bf16 (pre-converted).
// mode 1: bf16 out + RoPE. mode 2: bf16 transposed out. mode 3: A = sum of 4 bf16
// partials (P0..P3), fp32 out.
__global__ __launch_bounds__(256) void gemm_kernel(
    const unsigned short* __restrict__ A16,
    const unsigned short* __restrict__ P0, const unsigned short* __restrict__ P1,
    const unsigned short* __restrict__ P2, const unsigned short* __restrict__ P3,
    const unsigned short* __restrict__ W16,
    const float* __restrict__ bias, void* __restrict__ outv,
    const float* __restrict__ rope, const int* __restrict__ pos_ids, int mode)
{
  __shared__ short As[64][40];
  __shared__ short Ws[128][40];
  __shared__ float Cs[64][133];

  int t = threadIdx.x;
  int lane = t & 63, wave = t >> 6;
  int l15 = lane & 15, quad = lane >> 4;
  int wm = wave >> 1, wn = wave & 1;
  int row0 = blockIdx.y << 6;
  int col0 = blockIdx.x << 7;

  v4f acc[2][4];
  #pragma unroll
  for (int i = 0; i < 2; i++)
    #pragma unroll
    for (int j = 0; j < 4; j++)
      acc[i][j] = (v4f){0.f, 0.f, 0.f, 0.f};

  int ar = t >> 2, ac = (t & 3) * 8;
  int wr = t >> 1, wc = (t & 1) * 16;

  for (int kt = 0; kt < 1024; kt += 32){
    size_t aidx = (size_t)(row0 + ar)*1024 + kt + ac;
    if (mode == 3){
      v8s x0 = *(const v8s*)(P0 + aidx);
      v8s x1 = *(const v8s*)(P1 + aidx);
      v8s x2 = *(const v8s*)(P2 + aidx);
      v8s x3 = *(const v8s*)(P3 + aidx);
      v8s o;
      #pragma unroll
      for (int jj = 0; jj < 8; jj++)
        o[jj] = f2bfs(bfl(x0[jj]) + bfl(x1[jj]) + bfl(x2[jj]) + bfl(x3[jj]));
      *(v8s*)&As[ar][ac] = o;
    } else {
      *(v8s*)&As[ar][ac] = *(const v8s*)(A16 + aidx);
    }
    size_t widx = (size_t)(col0 + wr)*1024 + kt + wc;
    *(v8s*)&Ws[wr][wc]     = *(const v8s*)(W16 + widx);
    *(v8s*)&Ws[wr][wc + 8] = *(const v8s*)(W16 + widx + 8);
    __syncthreads();

    v8s af[2], bfq[4];
    #pragma unroll
    for (int i = 0; i < 2; i++) af[i]  = *(v8s*)&As[wm*32 + i*16 + l15][quad*8];
    #pragma unroll
    for (int j = 0; j < 4; j++) bfq[j] = *(v8s*)&Ws[wn*64 + j*16 + l15][quad*8];
    #pragma unroll
    for (int i = 0; i < 2; i++)
      #pragma unroll
      for (int j = 0; j < 4; j++)
        acc[i][j] = __builtin_amdgcn_mfma_f32_16x16x32_bf16(af[i], bfq[j], acc[i][j], 0, 0, 0);
    __syncthreads();
  }

  #pragma unroll
  for (int i = 0; i < 2; i++)
    #pragma unroll
    for (int j = 0; j < 4; j++)
      #pragma unroll
      for (int r = 0; r < 4; r++)
        Cs[wm*32 + i*16 + quad*4 + r][wn*64 + j*16 + l15] = acc[i][j][r];
  __syncthreads();

  if (mode == 2){
    unsigned short* o16 = (unsigned short*)outv;
    #pragma unroll
    for (int jj = 0; jj < 32; jj++){
      int flat = t + jj*256;
      int sl = flat & 63, c = flat >> 6;
      int grow = row0 + sl, gcol = col0 + c;
      float x = Cs[sl][c] + bias[gcol];
      int bb = grow >> 10, s = grow & 1023;
      o16[((size_t)(bb*1024 + gcol))*1024 + s] = (unsigned short)f2bfs(x);
    }
  } else if (mode == 1){
    unsigned short* o16 = (unsigned short*)outv;
    #pragma unroll
    for (int jj = 0; jj < 32; jj++){
      int flat = t + jj*256;
      int r = flat >> 7, c = flat & 127;
      int grow = row0 + r, gcol = col0 + c;
      float x = Cs[r][c] + bias[gcol];
      float p = Cs[r][c ^ 32] + bias[gcol ^ 32];
      int pos = pos_ids[grow];
      pos = pos < 0 ? 0 : (pos > 2047 ? 2047 : pos);
      int i = c & 31;
      float cs = rope[pos*64 + i];
      float sn = rope[pos*64 + 32 + i];
      x = ((c & 32) == 0) ? (x*cs - p*sn) : (x*cs + p*sn);
      o16[(size_t)grow*1024 + gcol] = (unsigned short)f2bfs(x);
    }
  } else {
    float* o32 = (float*)outv;
    #pragma unroll
    for (int jj = 0; jj < 32; jj++){
      int flat = t + jj*256;
      int r = flat >> 7, c = flat & 127;
      int grow = row0 + r, gcol = col0 + c;
      o32[(size_t)grow*1024 + gcol] = Cs[r][c] + bias[gcol];
    }
  }
}

// ---------- attention pass 1: scores + (M,l) partials; 512 blocks = (b,qt,quarter) ----------
__global__ __launch_bounds__(1024) void attn_pass1(
    const unsigned short* __restrict__ qw, const unsigned short* __restrict__ kw,
    const float* __restrict__ relk, const float* __restrict__ wpre_g,
    unsigned short* __restrict__ Sp, float* __restrict__ Mp, float* __restrict__ Lp)
{
  __shared__ short U_t[512][40];
  __shared__ short W_l[16][16][48];
  __shared__ short relk_s[129][68];

  int t = threadIdx.x;
  int h = t >> 6, lane = t & 63;
  int l15 = lane & 15, quad = lane >> 4;
  int bid = blockIdx.x;
  int quarter = bid & 3;
  int b = (bid >> 2) & 1;
  int qt = 63 - (bid >> 3);
  int q0 = qt << 4;
  int nkt = (qt + 2) >> 1;
  int hq = qt >> 1;
  int offt = hq*(hq+1) + ((qt & 1) ? (hq + 1) : 0);
  unsigned short* Sbase = Sp + ((size_t)(b*1056 + offt)) * 8192;

  { int* p0 = (int*)U_t; for (int e = t; e < 10240; e += 1024) p0[e] = 0; }
  for (int e = t; e < 129*64; e += 1024)
    relk_s[e >> 6][e & 63] = f2bfs(relk[(size_t)(128 + (e >> 6))*64 + (e & 63)]);

  v8s awp;
  #pragma unroll
  for (int jj = 0; jj < 8; jj++){
    int n = quad*8 + jj;
    awp[jj] = (n < 16) ? f2bfs(wpre_g[n*16 + l15]) : (short)0;
  }
  v8s aq[2];
  {
    const unsigned short* qb = qw + ((size_t)(b*SEQ + q0 + l15))*1024 + h*64;
    #pragma unroll
    for (int c = 0; c < 2; c++) aq[c] = *(const v8s*)(qb + c*32 + quad*8);
  }
  __syncthreads();

  v4f cinf = (v4f){0.f,0.f,0.f,0.f};
  #pragma unroll
  for (int c = 0; c < 2; c++){
    v8s binf = *(v8s*)&relk_s[128][c*32 + quad*8];
    cinf = __builtin_amdgcn_mfma_f32_16x16x32_bf16(aq[c], binf, cinf, 0, 0, 0);
  }

  float M_st[4] = {-1e30f, -1e30f, -1e30f, -1e30f};
  float l_st[4] = {0.f, 0.f, 0.f, 0.f};

  v8s kc[2][2];
  if (quarter < nkt){
    int k0 = quarter << 5;
    #pragma unroll
    for (int ct = 0; ct < 2; ct++){
      const unsigned short* kb = kw + ((size_t)(b*SEQ + k0 + ct*16 + l15))*1024 + h*64;
      #pragma unroll
      for (int c = 0; c < 2; c++) kc[ct][c] = *(const v8s*)(kb + c*32 + quad*8);
    }
  }

  for (int ci = quarter; ci < nkt; ci += 4){
    int k0 = ci << 5;
    int r_lo = q0 - k0 - 31;
    bool far = (r_lo >= 128);

    v4f cqk[2];
    #pragma unroll
    for (int ct = 0; ct < 2; ct++){
      v4f acc = (v4f){0.f,0.f,0.f,0.f};
      #pragma unroll
      for (int c = 0; c < 2; c++)
        acc = __builtin_amdgcn_mfma_f32_16x16x32_bf16(aq[c], kc[ct][c], acc, 0, 0, 0);
      cqk[ct] = acc;
    }
    v8s kn[2][2];
    {
      int cin = ci + 4;
      int k0n = ((cin < nkt) ? cin : ci) << 5;
      #pragma unroll
      for (int ct = 0; ct < 2; ct++){
        const unsigned short* kb = kw + ((size_t)(b*SEQ + k0n + ct*16 + l15))*1024 + h*64;
        #pragma unroll
        for (int c = 0; c < 2; c++) kn[ct][c] = *(const v8s*)(kb + c*32 + quad*8);
      }
    }

    if (!far){
      #pragma unroll
      for (int pt = 0; pt < 3; pt++){
        int rr = r_lo + pt*16 + l15; rr = rr < 0 ? 0 : (rr > 128 ? 128 : rr);
        v4f acc = (v4f){0.f,0.f,0.f,0.f};
        #pragma unroll
        for (int c = 0; c < 2; c++){
          v8s rv = *(v8s*)&relk_s[rr][c*32 + quad*8];
          acc = __builtin_amdgcn_mfma_f32_16x16x32_bf16(aq[c], rv, acc, 0, 0, 0);
        }
        #pragma unroll
        for (int reg = 0; reg < 4; reg++)
          W_l[h][quad*4 + reg][pt*16 + l15] = f2bfs(acc[reg]);
      }
    }
    #pragma unroll
    for (int ct = 0; ct < 2; ct++)
      #pragma unroll
      for (int reg = 0; reg < 4; reg++){
        int i = quad*4 + reg, j = ct*16 + l15;
        float wv = far ? cinf[reg] : bfl(W_l[h][i][i - j + 31]);
        U_t[i*32 + j][h] = f2bfs((cqk[ct][reg] + wv) * 0.125f);
      }
    __syncthreads();   // B1: U ready

    v4f cs[2];
    #pragma unroll
    for (int ct = 0; ct < 2; ct++){
      v8s bu = *(v8s*)&U_t[h*32 + ct*16 + l15][quad*8];
      cs[ct] = __builtin_amdgcn_mfma_f32_16x16x32_bf16(awp, bu, (v4f){0.f,0.f,0.f,0.f}, 0, 0, 0);
    }
    short sb[2][4];
    unsigned short* stile = Sbase + (size_t)ci * 8192;
    #pragma unroll
    for (int ct = 0; ct < 2; ct++){
      #pragma unroll
      for (int reg = 0; reg < 4; reg++) sb[ct][reg] = f2bfs(cs[ct][reg]);
      uint2 pk;
      pk.x = ((unsigned int)(unsigned short)sb[ct][0]) | (((unsigned int)(unsigned short)sb[ct][1]) << 16);
      pk.y = ((unsigned int)(unsigned short)sb[ct][2]) | (((unsigned int)(unsigned short)sb[ct][3]) << 16);
      *(uint2*)(stile + ((size_t)((h*2 + ct)*64 + quad*16 + l15))*4) = pk;
    }
    bool v0 = (k0 + l15)      <= (q0 + h);
    bool v1 = (k0 + 16 + l15) <= (q0 + h);
    #pragma unroll
    for (int reg = 0; reg < 4; reg++){
      float s0 = v0 ? bfl(sb[0][reg]) : -1e4f;
      float s1 = v1 ? bfl(sb[1][reg]) : -1e4f;
      float mx = fmaxf(s0, s1);
      mx = fmaxf(mx, __shfl_xor(mx, 1, 64));
      mx = fmaxf(mx, __shfl_xor(mx, 2, 64));
      mx = fmaxf(mx, __shfl_xor(mx, 4, 64));
      mx = fmaxf(mx, __shfl_xor(mx, 8, 64));
      float Mn = fmaxf(M_st[reg], mx);
      float al = __expf(fmaxf(M_st[reg] - Mn, -100.f));
      M_st[reg] = Mn;
      float p0 = v0 ? __expf(s0 - Mn) : 0.f;
      float p1 = v1 ? __expf(s1 - Mn) : 0.f;
      float sm = p0 + p1;
      sm += __shfl_xor(sm, 1, 64);
      sm += __shfl_xor(sm, 2, 64);
      sm += __shfl_xor(sm, 4, 64);
      sm += __shfl_xor(sm, 8, 64);
      l_st[reg] = l_st[reg]*al + sm;
    }
    __syncthreads();   // B2: U reusable
    #pragma unroll
    for (int ct = 0; ct < 2; ct++)
      #pragma unroll
      for (int c = 0; c < 2; c++) kc[ct][c] = kn[ct][c];
  }

  size_t pb = ((((size_t)b*64 + qt)*4 + quarter)*16 + h)*16;
  if (l15 == 0){
    #pragma unroll
    for (int reg = 0; reg < 4; reg++){
      Mp[pb + quad*4 + reg] = M_st[reg];
      Lp[pb + quad*4 + reg] = l_st[reg];
    }
  }
}

// ---------- attention pass 2: exact attn from S', post-mix, PV + rel_v ----------
__global__ __launch_bounds__(1024) void attn_pass2(
    const unsigned short* __restrict__ Sp, const unsigned short* __restrict__ vwT,
    const float* __restrict__ relv, const float* __restrict__ wpost_g,
    const float* __restrict__ Mp, const float* __restrict__ Lp,
    unsigned short* __restrict__ c0, unsigned short* __restrict__ c1,
    unsigned short* __restrict__ c2, unsigned short* __restrict__ c3)
{
  __shared__ short U_t[512][40];
  __shared__ short Pp[16][16][40];
  __shared__ short Tt[16][16][72];
  __shared__ short relv_s[129][66];
  __shared__ float M_f[16][17], il_f[16][17], Srow[16][17];

  int t = threadIdx.x;
  int h = t >> 6, lane = t & 63;
  int l15 = lane & 15, quad = lane >> 4;
  int bid = blockIdx.x;
  int quarter = bid & 3;
  int b = (bid >> 2) & 1;
  int qt = 63 - (bid >> 3);
  int q0 = qt << 4;
  int nkt = (qt + 2) >> 1;
  int hq = qt >> 1;
  int offt = hq*(hq+1) + ((qt & 1) ? (hq + 1) : 0);
  const unsigned short* Sbase = Sp + ((size_t)(b*1056 + offt)) * 8192;
  unsigned short* ctx = (quarter == 0) ? c0 : (quarter == 1) ? c1 : (quarter == 2) ? c2 : c3;

  { int* p0 = (int*)U_t; for (int e = t; e < 10240; e += 1024) p0[e] = 0; }
  { int* p1 = (int*)Tt;  for (int e = t; e < 9216;  e += 1024) p1[e] = 0; }
  for (int e = t; e < 129*64; e += 1024)
    relv_s[e >> 6][e & 63] = f2bfs(relv[(size_t)(128 + (e >> 6))*64 + (e & 63)]);
  if (t < 256){
    int i = t >> 4, n = t & 15;
    Srow[i][n] = 0.f;
    size_t b0 = ((((size_t)b*64 + qt)*4 + 0)*16 + i)*16 + n;
    float M = Mp[b0];
    #pragma unroll
    for (int qd = 1; qd < 4; qd++) M = fmaxf(M, Mp[b0 + qd*256]);
    float l = 0.f;
    #pragma unroll
    for (int qd = 0; qd < 4; qd++)
      l += Lp[b0 + qd*256] * __expf(Mp[b0 + qd*256] - M);
    M_f[i][n]  = M;
    il_f[i][n] = 1.f / l;
  }
  v8s awq;
  #pragma unroll
  for (int jj = 0; jj < 8; jj++){
    int n = quad*8 + jj;
    awq[jj] = (n < 16) ? f2bfs(wpost_g[n*16 + l15]) : (short)0;
  }
  __syncthreads();

  v4f o_acc[4];
  #pragma unroll
  for (int dt = 0; dt < 4; dt++) o_acc[dt] = (v4f){0.f,0.f,0.f,0.f};

  const unsigned short* vtb = vwT + ((size_t)(b*1024 + h*64))*1024;

  uint4 sv;
  if (quarter < nkt) sv = *(const uint4*)(Sbase + (size_t)quarter*8192 + (size_t)t*8);

  for (int ci = quarter; ci < nkt; ci += 4){
    int k0 = ci << 5;
    int r_lo = q0 - k0 - 31;
    bool far = (r_lo >= 128);

    #pragma unroll
    for (int g = 0; g < 2; g++){
      unsigned int w0 = (g == 0) ? sv.x : sv.z;
      unsigned int w1 = (g == 0) ? sv.y : sv.w;
      int v = t*2 + g;
      int i = v >> 7, ct = (v >> 6) & 1, quadv = (v >> 4) & 3, lv = v & 15;
      int j = ct*16 + lv;
      bool valid = (k0 + j) <= (q0 + i);
      v4s_t at;
      unsigned short ss[4] = { (unsigned short)(w0 & 0xffff), (unsigned short)(w0 >> 16),
                               (unsigned short)(w1 & 0xffff), (unsigned short)(w1 >> 16) };
      #pragma unroll
      for (int reg = 0; reg < 4; reg++){
        int n = quadv*4 + reg;
        float a = valid ? __expf(bfl((short)ss[reg]) - M_f[i][n]) * il_f[i][n] : 0.f;
        at[reg] = f2bfs(a);
      }
      *(v4s_t*)&U_t[i*32 + j][quadv*4] = at;
    }
    __syncthreads();   // B1: At ready

    v4f cp[2];
    #pragma unroll
    for (int ct = 0; ct < 2; ct++){
      v8s bu = *(v8s*)&U_t[h*32 + ct*16 + l15][quad*8];
      cp[ct] = __builtin_amdgcn_mfma_f32_16x16x32_bf16(awq, bu, (v4f){0.f,0.f,0.f,0.f}, 0, 0, 0);
    }
    #pragma unroll
    for (int ct = 0; ct < 2; ct++)
      #pragma unroll
      for (int reg = 0; reg < 4; reg++){
        int n = quad*4 + reg, j = ct*16 + l15;
        short pb = f2bfs(cp[ct][reg]);
        Pp[n][h][j] = pb;
        if (!far) Tt[n][h][h + 31 - j] = pb;
      }
    if (far){
      #pragma unroll
      for (int reg = 0; reg < 4; reg++){
        float s = cp[0][reg] + cp[1][reg];
        s += __shfl_xor(s, 1, 64);
        s += __shfl_xor(s, 2, 64);
        s += __shfl_xor(s, 4, 64);
        s += __shfl_xor(s, 8, 64);
        if (l15 == 0) Srow[quad*4 + reg][h] += s;
      }
    }
    __syncthreads();   // B2: Pp/Tt/Srow ready

    {
      int cin = ci + 4;
      int cld = (cin < nkt) ? cin : ci;
      sv = *(const uint4*)(Sbase + (size_t)cld*8192 + (size_t)t*8);
    }

    v8s ap = *(v8s*)&Pp[h][l15][quad*8];
    #pragma unroll
    for (int dt = 0; dt < 4; dt++){
      v8s bv = *(const v8s*)(vtb + (size_t)(dt*16 + l15)*1024 + k0 + quad*8);
      o_acc[dt] = __builtin_amdgcn_mfma_f32_16x16x32_bf16(ap, bv, o_acc[dt], 0, 0, 0);
    }
    if (!far){
      #pragma unroll
      for (int ch = 0; ch < 2; ch++){
        v8s at2 = *(v8s*)&Tt[h][l15][ch*32 + quad*8];
        #pragma unroll
        for (int dt = 0; dt < 4; dt++){
          v8s br;
          #pragma unroll
          for (int jj = 0; jj < 8; jj++){
            int rr = r_lo + ch*32 + quad*8 + jj;
            rr = rr < 0 ? 0 : (rr > 128 ? 128 : rr);
            br[jj] = relv_s[rr][dt*16 + l15];
          }
          o_acc[dt] = __builtin_amdgcn_mfma_f32_16x16x32_bf16(at2, br, o_acc[dt], 0, 0, 0);
        }
      }
    }
  }
  __syncthreads();   // Srow final

  #pragma unroll
  for (int dt = 0; dt < 4; dt++)
    #pragma unroll
    for (int reg = 0; reg < 4; reg++){
      float o = o_acc[dt][reg] + Srow[h][quad*4 + reg] * bfl(relv_s[128][dt*16 + l15]);
      ctx[((size_t)(b*SEQ + q0 + quad*4 + reg))*1024 + h*64 + dt*16 + l15] = (unsigned short)f2bfs(o);
    }
}

extern "C" void kernel_launch(void* const* d_in, const int* in_sizes, int n_in,
                              void* d_out, int out_size, void* d_ws, size_t ws_size,
                              hipStream_t stream)
{
  int ip = -1;
  for (int i = 0; i < n_in; i++){
    if (in_sizes[i] == 2048){ ip = i; break; }
  }
  if (ip < 0) ip = 4;

  const float* query = (const float*)d_in[0];
  const float* key   = (const float*)d_in[1];
  const float* value = (const float*)d_in[2];
  const int* qpos = (const int*)d_in[ip];
  const int* kpos = (const int*)d_in[ip + 1];
  const float* Wq    = (const float*)d_in[ip + 2];
  const float* bq    = (const float*)d_in[ip + 3];
  const float* Wk    = (const float*)d_in[ip + 4];
  const float* bk    = (const float*)d_in[ip + 5];
  const float* Wv    = (const float*)d_in[ip + 6];
  const float* b_v   = (const float*)d_in[ip + 7];
  const float* Wo    = (const float*)d_in[ip + 8];
  const float* bo    = (const float*)d_in[ip + 9];
  const float* relk  = (const float*)d_in[ip + 10];
  const float* relv  = (const float*)d_in[ip + 11];
  const float* wpre  = (const float*)d_in[ip + 12];
  const float* wpost = (const float*)d_in[ip + 13];

  char* ws = (char*)d_ws;
  float* rope           = (float*)ws;                                   // 524,288 B
  unsigned short* conv  = (unsigned short*)(ws + 524288);               // 20,971,520 B
  unsigned short* qbf   = conv;
  unsigned short* kbf   = conv + 2097152;
  unsigned short* vbf   = conv + 4194304;
  unsigned short* wqbf  = conv + 6291456;
  unsigned short* wkbf  = conv + 7340032;
  unsigned short* wvbf  = conv + 8388608;
  unsigned short* wobf  = conv + 9437184;
  unsigned short* q_ws  = (unsigned short*)(ws + 21495808);             // 4 MB each
  unsigned short* k_ws  = (unsigned short*)(ws + 25690112);
  unsigned short* v_ws  = (unsigned short*)(ws + 29884416);             // transposed
  unsigned short* ctx0  = (unsigned short*)(ws + 34078720);             // 4 MB bf16 each
  unsigned short* ctx1  = (unsigned short*)(ws + 38273024);
  unsigned short* ctx2  = (unsigned short*)(ws + 42467328);
  unsigned short* ctx3  = (unsigned short*)(ws + 46661632);
  unsigned short* Sp    = (unsigned short*)(ws + 50855936);             // 34,603,008 B
  float* Mp             = (float*)(ws + 85458944);                      // 524,288 B
  float* Lp             = (float*)(ws + 85983232);                      // 524,288 B

  hipLaunchKernelGGL(rope_table_kernel, dim3(256), dim3(256), 0, stream, rope);
  hipLaunchKernelGGL(conv_kernel, dim3(5120), dim3(256), 0, stream,
                     query, key, value, Wq, Wk, Wv, Wo, conv);
  dim3 gg(8, 32);
  hipLaunchKernelGGL(gemm_kernel, gg, dim3(256), 0, stream,
                     qbf, qbf, qbf, qbf, qbf, wqbf, bq, (void*)q_ws, rope, qpos, 1);
  hipLaunchKernelGGL(gemm_kernel, gg, dim3(256), 0, stream,
                     kbf, kbf, kbf, kbf, kbf, wkbf, bk, (void*)k_ws, rope, kpos, 1);
  hipLaunchKernelGGL(gemm_kernel, gg, dim3(256), 0, stream,
                     vbf, vbf, vbf, vbf, vbf, wvbf, b_v, (void*)v_ws, rope, qpos, 2);
  hipLaunchKernelGGL(attn_pass1, dim3(512), dim3(1024), 0, stream,
                     q_ws, k_ws, relk, wpre, Sp, Mp, Lp);
  hipLaunchKernelGGL(attn_pass2, dim3(512), dim3(1024), 0, stream,
                     Sp, v_ws, relv, wpost, Mp, Lp, ctx0, ctx1, ctx2, ctx3);
  hipLaunchKernelGGL(gemm_kernel, gg, dim3(256), 0, stream,
                     ctx0, ctx0, ctx1, ctx2, ctx3, wobf, bo, d_out, rope, qpos, 3);
}